// Round 1
// baseline (773.144 us; speedup 1.0000x reference)
//
#include <hip/hip_runtime.h>
#include <hip/hip_bf16.h>

#define BATCHN 2
#define SEQL 1000
#define DMODEL 1024
#define DSTATE 128
#define HEADDIM 64
#define CHUNKL 10
#define DINNER 2048
#define NHEADS 32
#define CONVDIM 2304   // DINNER + 2*DSTATE
#define NPROJ 4384     // 2*DINNER + 2*DSTATE + NHEADS
#define TOKENS 2000
#define NCHUNK 100

typedef __bf16 bfx8 __attribute__((ext_vector_type(8)));
typedef float fx4 __attribute__((ext_vector_type(4)));
typedef unsigned short u16x8 __attribute__((ext_vector_type(8)));

__device__ __forceinline__ unsigned short f2bf(float f) {
    unsigned int u = __builtin_bit_cast(unsigned int, f);
    u += 0x7FFFu + ((u >> 16) & 1u);
    return (unsigned short)(u >> 16);
}

// ---------------- fp32 -> bf16 conversion ----------------
__global__ __launch_bounds__(256) void k_f2bf(const float* __restrict__ src,
                                              unsigned short* __restrict__ dst, int n4) {
    int i = blockIdx.x * 256 + threadIdx.x;
    if (i >= n4) return;
    float4 v = ((const float4*)src)[i];
    ushort4 o;
    o.x = f2bf(v.x); o.y = f2bf(v.y); o.z = f2bf(v.z); o.w = f2bf(v.w);
    ((ushort4*)dst)[i] = o;
}

// ---------------- dt head projection in fp32 (exp-sensitive path) ----------------
__global__ __launch_bounds__(256) void k_dt(const float* __restrict__ x,
                                            const float* __restrict__ win,
                                            const float* __restrict__ dt_bias,
                                            float* __restrict__ dtv) {
    int idx = blockIdx.x * 256 + threadIdx.x;
    if (idx >= TOKENS * NHEADS) return;
    int tok = idx >> 5, h = idx & 31;
    const float4* xr = (const float4*)(x + (size_t)tok * DMODEL);
    const float4* wr = (const float4*)(win + (size_t)(2 * DINNER + 2 * DSTATE + h) * DMODEL);
    float acc = 0.f;
    #pragma unroll 4
    for (int k = 0; k < DMODEL / 4; ++k) {
        float4 a = xr[k], b = wr[k];
        acc += a.x * b.x + a.y * b.y + a.z * b.z + a.w * b.w;
    }
    float v = acc + dt_bias[h];
    // softplus
    dtv[idx] = fmaxf(v, 0.f) + log1pf(expf(-fabsf(v)));
}

// ---------------- bf16 NT GEMM: C[M][N] = A[M][K] * B[N][K]^T ----------------
__global__ __launch_bounds__(256) void k_gemm_nt(const unsigned short* __restrict__ A,
                                                 const unsigned short* __restrict__ B,
                                                 float* __restrict__ C,
                                                 int M, int N, int K) {
    __shared__ __attribute__((aligned(16))) unsigned short As[64][40];
    __shared__ __attribute__((aligned(16))) unsigned short Bs[64][40];
    int t = threadIdx.x;
    int lane = t & 63, wave = t >> 6;
    int wr = wave >> 1, wc = wave & 1;
    int m0 = blockIdx.y * 64, n0 = blockIdx.x * 64;
    int lr = t >> 2, lk = (t & 3) * 8;
    int fr = lane & 15, fk = (lane >> 4) * 8;
    fx4 acc00 = {0.f, 0.f, 0.f, 0.f}, acc01 = {0.f, 0.f, 0.f, 0.f};
    fx4 acc10 = {0.f, 0.f, 0.f, 0.f}, acc11 = {0.f, 0.f, 0.f, 0.f};
    for (int k0 = 0; k0 < K; k0 += 32) {
        u16x8 av = {0, 0, 0, 0, 0, 0, 0, 0};
        u16x8 bv = {0, 0, 0, 0, 0, 0, 0, 0};
        int ar = m0 + lr;
        if (ar < M) av = *(const u16x8*)(A + (size_t)ar * K + k0 + lk);
        int br = n0 + lr;
        if (br < N) bv = *(const u16x8*)(B + (size_t)br * K + k0 + lk);
        __syncthreads();
        *(u16x8*)(&As[lr][lk]) = av;
        *(u16x8*)(&Bs[lr][lk]) = bv;
        __syncthreads();
        bfx8 a0 = *(const bfx8*)(&As[wr * 32 + fr][fk]);
        bfx8 a1 = *(const bfx8*)(&As[wr * 32 + 16 + fr][fk]);
        bfx8 b0 = *(const bfx8*)(&Bs[wc * 32 + fr][fk]);
        bfx8 b1 = *(const bfx8*)(&Bs[wc * 32 + 16 + fr][fk]);
        acc00 = __builtin_amdgcn_mfma_f32_16x16x32_bf16(a0, b0, acc00, 0, 0, 0);
        acc01 = __builtin_amdgcn_mfma_f32_16x16x32_bf16(a0, b1, acc01, 0, 0, 0);
        acc10 = __builtin_amdgcn_mfma_f32_16x16x32_bf16(a1, b0, acc10, 0, 0, 0);
        acc11 = __builtin_amdgcn_mfma_f32_16x16x32_bf16(a1, b1, acc11, 0, 0, 0);
    }
    int orow = m0 + wr * 32 + (lane >> 4) * 4;
    int ocol = n0 + wc * 32 + fr;
    #pragma unroll
    for (int i = 0; i < 4; ++i) {
        int r0 = orow + i;
        if (r0 < M) {
            if (ocol < N)      C[(size_t)r0 * N + ocol] = acc00[i];
            if (ocol + 16 < N) C[(size_t)r0 * N + ocol + 16] = acc01[i];
        }
        int r1 = orow + 16 + i;
        if (r1 < M) {
            if (ocol < N)      C[(size_t)r1 * N + ocol] = acc10[i];
            if (ocol + 16 < N) C[(size_t)r1 * N + ocol + 16] = acc11[i];
        }
    }
}

// ---------------- depthwise causal conv (width 4) + bias + SiLU ----------------
__global__ __launch_bounds__(256) void k_conv(const float* __restrict__ zx,
                                              const float* __restrict__ cw,
                                              const float* __restrict__ cb,
                                              float* __restrict__ xbc) {
    int idx = blockIdx.x * 256 + threadIdx.x;
    if (idx >= TOKENS * CONVDIM) return;
    int row = idx / CONVDIM;
    int col = idx - row * CONVDIM;
    int l = row % SEQL;
    float acc = cb[col];
    #pragma unroll
    for (int j = 0; j < 4; ++j) {
        int lj = l - 3 + j;
        if (lj >= 0)
            acc += zx[(size_t)(row - 3 + j) * NPROJ + DINNER + col] * cw[col * 4 + j];
    }
    xbc[idx] = acc / (1.f + expf(-acc));
}

// ---------------- sequential chunk scan per (batch, head): writes Y_off ----------------
__global__ __launch_bounds__(256) void k_scan(const float* __restrict__ xbc,
                                              const float* __restrict__ dtv,
                                              const float* __restrict__ A_log,
                                              float* __restrict__ ybuf) {
    int b = blockIdx.x >> 5, h = blockIdx.x & 31;
    float A = -expf(A_log[h]);
    int t = threadIdx.x;
    int p = t & 63, nq = t >> 6;
    int n0 = nq * 32;
    float S[32];
    #pragma unroll
    for (int i = 0; i < 32; ++i) S[i] = 0.f;
    __shared__ float sB[10][128], sC[10][128], sx[10][64];
    __shared__ float sdA[10], sdt[10];
    __shared__ float part[10][64][5];
    for (int c = 0; c < NCHUNK; ++c) {
        int tok0 = b * SEQL + c * CHUNKL;
        for (int i = t; i < 1280; i += 256) {
            int l = i >> 7, n = i & 127;
            sB[l][n] = xbc[(size_t)(tok0 + l) * CONVDIM + DINNER + n];
            sC[l][n] = xbc[(size_t)(tok0 + l) * CONVDIM + DINNER + DSTATE + n];
        }
        for (int i = t; i < 640; i += 256) {
            int l = i >> 6, pp = i & 63;
            sx[l][pp] = xbc[(size_t)(tok0 + l) * CONVDIM + h * 64 + pp];
        }
        if (t < 10) {
            float d = dtv[(size_t)(tok0 + t) * NHEADS + h];
            sdt[t] = d;
            sdA[t] = A * d;
        }
        __syncthreads();
        float Acs[10];
        {
            float run = 0.f;
            #pragma unroll
            for (int l = 0; l < 10; ++l) { run += sdA[l]; Acs[l] = run; }
        }
        float csum = Acs[9];
        // Y_off partial: sum_n C[l][n] * S[p][n] over this thread's 32 n's
        #pragma unroll
        for (int l = 0; l < 10; ++l) {
            float acc = 0.f;
            #pragma unroll
            for (int i = 0; i < 32; ++i) acc += sC[l][n0 + i] * S[i];
            part[l][p][nq] = acc;
        }
        __syncthreads();
        for (int i = t; i < 640; i += 256) {
            int l = i >> 6, pp = i & 63;
            float v = (part[l][pp][0] + part[l][pp][1] + part[l][pp][2] + part[l][pp][3]) * expf(Acs[l]);
            ybuf[(size_t)(tok0 + l) * DINNER + h * 64 + pp] = v;
        }
        // state update: S = exp(csum)*S + sum_l B[l][n] * exp(csum - Acs[l]) * x[l][p]*dt[l]
        float a[10];
        #pragma unroll
        for (int l = 0; l < 10; ++l) a[l] = sx[l][p] * sdt[l] * expf(csum - Acs[l]);
        float cs = expf(csum);
        #pragma unroll
        for (int i = 0; i < 32; ++i) {
            float v = S[i] * cs;
            #pragma unroll
            for (int l = 0; l < 10; ++l) v += a[l] * sB[l][n0 + i];
            S[i] = v;
        }
        __syncthreads();
    }
}

// ---------------- per-chunk diagonal block + D*x, added into ybuf ----------------
__global__ __launch_bounds__(256) void k_diag(const float* __restrict__ xbc,
                                              const float* __restrict__ dtv,
                                              const float* __restrict__ A_log,
                                              const float* __restrict__ Dp,
                                              float* __restrict__ ybuf) {
    int bc = blockIdx.x >> 2;
    int hg = blockIdx.x & 3;
    int b = bc / NCHUNK, c = bc - b * NCHUNK;
    int tok0 = b * SEQL + c * CHUNKL;
    int t = threadIdx.x;
    __shared__ float sB[10][128], sC[10][128], sxr[10][512];
    __shared__ float sdt[10][8], sdA[10][8];
    __shared__ float sG[10][10], sW[10][10];
    for (int i = t; i < 1280; i += 256) {
        int l = i >> 7, n = i & 127;
        sB[l][n] = xbc[(size_t)(tok0 + l) * CONVDIM + DINNER + n];
        sC[l][n] = xbc[(size_t)(tok0 + l) * CONVDIM + DINNER + DSTATE + n];
    }
    for (int i = t; i < 5120; i += 256) {
        int l = i >> 9, q = i & 511;
        sxr[l][q] = xbc[(size_t)(tok0 + l) * CONVDIM + hg * 512 + q];
    }
    if (t < 80) {
        int l = t >> 3, hh = t & 7;
        int h = hg * 8 + hh;
        float d = dtv[(size_t)(tok0 + l) * NHEADS + h];
        sdt[l][hh] = d;
        sdA[l][hh] = -expf(A_log[h]) * d;
    }
    __syncthreads();
    if (t < 100) {
        int l = t / 10, s = t - (t / 10) * 10;
        float acc = 0.f;
        for (int n = 0; n < 128; ++n) acc += sC[l][n] * sB[s][n];
        sG[l][s] = acc;
    }
    __syncthreads();
    for (int hh = 0; hh < 8; ++hh) {
        int h = hg * 8 + hh;
        if (t < 100) {
            int l = t / 10, s = t - (t / 10) * 10;
            if (s <= l) {
                float cum = 0.f;
                for (int k = s + 1; k <= l; ++k) cum += sdA[k][hh];
                sW[l][s] = sG[l][s] * expf(cum);
            } else {
                sW[l][s] = 0.f;
            }
        }
        __syncthreads();
        float Dh = Dp[h];
        for (int i = t; i < 640; i += 256) {
            int l = i >> 6, pp = i & 63;
            float acc = 0.f;
            for (int s = 0; s <= l; ++s) acc += sW[l][s] * sxr[s][hh * 64 + pp] * sdt[s][hh];
            size_t off = (size_t)(tok0 + l) * DINNER + h * 64 + pp;
            ybuf[off] = ybuf[off] + acc + Dh * sxr[l][hh * 64 + pp];
        }
        __syncthreads();
    }
}

// ---------------- gate (y * silu(z)) + RMSNorm + norm_w, output bf16 ----------------
__global__ __launch_bounds__(256) void k_norm(const float* __restrict__ ybuf,
                                              const float* __restrict__ zx,
                                              const float* __restrict__ normw,
                                              unsigned short* __restrict__ ynb) {
    int row = blockIdx.x;
    int t = threadIdx.x;
    float v[8];
    float ss = 0.f;
    #pragma unroll
    for (int j = 0; j < 8; ++j) {
        int col = t + j * 256;
        float y = ybuf[(size_t)row * DINNER + col];
        float z = zx[(size_t)row * NPROJ + col];
        y *= z / (1.f + expf(-z));
        v[j] = y;
        ss += y * y;
    }
    #pragma unroll
    for (int off = 32; off > 0; off >>= 1) ss += __shfl_down(ss, off, 64);
    __shared__ float red[4];
    int lane = t & 63, wv = t >> 6;
    if (lane == 0) red[wv] = ss;
    __syncthreads();
    float tot = red[0] + red[1] + red[2] + red[3];
    float r = rsqrtf(tot * (1.f / DINNER) + 1e-5f);
    #pragma unroll
    for (int j = 0; j < 8; ++j) {
        int col = t + j * 256;
        ynb[(size_t)row * DINNER + col] = f2bf(v[j] * r * normw[col]);
    }
}

extern "C" void kernel_launch(void* const* d_in, const int* in_sizes, int n_in,
                              void* d_out, int out_size, void* d_ws, size_t ws_size,
                              hipStream_t stream) {
    const float* x       = (const float*)d_in[0];
    const float* W_in    = (const float*)d_in[1];
    const float* conv_w  = (const float*)d_in[2];
    const float* conv_b  = (const float*)d_in[3];
    const float* dt_bias = (const float*)d_in[4];
    const float* A_log   = (const float*)d_in[5];
    const float* Dp      = (const float*)d_in[6];
    const float* norm_w  = (const float*)d_in[7];
    const float* W_out   = (const float*)d_in[8];
    float* out = (float*)d_out;

    char* w = (char*)d_ws;
    auto alloc = [&](size_t bytes) {
        char* p = w;
        w += (bytes + 255) & ~(size_t)255;
        return p;
    };
    unsigned short* xb    = (unsigned short*)alloc((size_t)TOKENS * DMODEL * 2);
    unsigned short* winb  = (unsigned short*)alloc((size_t)NPROJ * DMODEL * 2);
    unsigned short* woutb = (unsigned short*)alloc((size_t)DMODEL * DINNER * 2);
    float* zx  = (float*)alloc((size_t)TOKENS * NPROJ * 4);
    float* xbc = (float*)alloc((size_t)TOKENS * CONVDIM * 4);
    float* dtv = (float*)alloc((size_t)TOKENS * NHEADS * 4);
    float* yb  = (float*)alloc((size_t)TOKENS * DINNER * 4);
    unsigned short* ynb = (unsigned short*)alloc((size_t)TOKENS * DINNER * 2);

    k_f2bf<<<(TOKENS * DMODEL / 4 + 255) / 256, 256, 0, stream>>>(x, xb, TOKENS * DMODEL / 4);
    k_f2bf<<<(NPROJ * DMODEL / 4 + 255) / 256, 256, 0, stream>>>(W_in, winb, NPROJ * DMODEL / 4);
    k_f2bf<<<(DMODEL * DINNER / 4 + 255) / 256, 256, 0, stream>>>(W_out, woutb, DMODEL * DINNER / 4);
    k_dt<<<(TOKENS * NHEADS + 255) / 256, 256, 0, stream>>>(x, W_in, dt_bias, dtv);
    dim3 g1((NPROJ + 63) / 64, (TOKENS + 63) / 64);
    k_gemm_nt<<<g1, 256, 0, stream>>>(xb, winb, zx, TOKENS, NPROJ, DMODEL);
    k_conv<<<(TOKENS * CONVDIM + 255) / 256, 256, 0, stream>>>(zx, conv_w, conv_b, xbc);
    k_scan<<<BATCHN * NHEADS, 256, 0, stream>>>(xbc, dtv, A_log, yb);
    k_diag<<<BATCHN * NCHUNK * 4, 256, 0, stream>>>(xbc, dtv, A_log, Dp, yb);
    k_norm<<<TOKENS, 256, 0, stream>>>(yb, zx, norm_w, ynb);
    dim3 g2((DMODEL + 63) / 64, (TOKENS + 63) / 64);
    k_gemm_nt<<<g2, 256, 0, stream>>>(ynb, woutb, out, TOKENS, DMODEL, DINNER);
}

// Round 2
// 324.878 us; speedup vs baseline: 2.3798x; 2.3798x over previous
//
#include <hip/hip_runtime.h>
#include <hip/hip_bf16.h>

#define BATCHN 2
#define SEQL 1000
#define DMODEL 1024
#define DSTATE 128
#define HEADDIM 64
#define CHUNKL 10
#define DINNER 2048
#define NHEADS 32
#define CONVDIM 2304   // DINNER + 2*DSTATE
#define NPROJ 4384     // 2*DINNER + 2*DSTATE + NHEADS
#define TOKENS 2000
#define NCHUNK 100
#define GROUPS 20      // groups per sequence
#define GCH 5          // chunks per group

typedef __bf16 bfx8 __attribute__((ext_vector_type(8)));
typedef float fx4 __attribute__((ext_vector_type(4)));
typedef unsigned short u16x8 __attribute__((ext_vector_type(8)));

__device__ __forceinline__ unsigned short f2bf(float f) {
    unsigned int u = __builtin_bit_cast(unsigned int, f);
    u += 0x7FFFu + ((u >> 16) & 1u);
    return (unsigned short)(u >> 16);
}

// ---------------- fp32 -> bf16 conversion ----------------
__global__ __launch_bounds__(256) void k_f2bf(const float* __restrict__ src,
                                              unsigned short* __restrict__ dst, int n4) {
    int i = blockIdx.x * 256 + threadIdx.x;
    if (i >= n4) return;
    float4 v = ((const float4*)src)[i];
    ushort4 o;
    o.x = f2bf(v.x); o.y = f2bf(v.y); o.z = f2bf(v.z); o.w = f2bf(v.w);
    ((ushort4*)dst)[i] = o;
}

// ---------------- dt head projection in fp32 (exp-sensitive path) ----------------
__global__ __launch_bounds__(256) void k_dt(const float* __restrict__ x,
                                            const float* __restrict__ win,
                                            const float* __restrict__ dt_bias,
                                            float* __restrict__ dtv) {
    int idx = blockIdx.x * 256 + threadIdx.x;
    if (idx >= TOKENS * NHEADS) return;
    int tok = idx >> 5, h = idx & 31;
    const float4* xr = (const float4*)(x + (size_t)tok * DMODEL);
    const float4* wr = (const float4*)(win + (size_t)(2 * DINNER + 2 * DSTATE + h) * DMODEL);
    float acc = 0.f;
    #pragma unroll 4
    for (int k = 0; k < DMODEL / 4; ++k) {
        float4 a = xr[k], b = wr[k];
        acc += a.x * b.x + a.y * b.y + a.z * b.z + a.w * b.w;
    }
    float v = acc + dt_bias[h];
    dtv[idx] = fmaxf(v, 0.f) + log1pf(expf(-fabsf(v)));
}

// ---------------- bf16 NT GEMM: C[M][N] = A[M][K] * B[N][K]^T ----------------
__global__ __launch_bounds__(256) void k_gemm_nt(const unsigned short* __restrict__ A,
                                                 const unsigned short* __restrict__ B,
                                                 float* __restrict__ C,
                                                 int M, int N, int K) {
    __shared__ __attribute__((aligned(16))) unsigned short As[64][40];
    __shared__ __attribute__((aligned(16))) unsigned short Bs[64][40];
    int t = threadIdx.x;
    int lane = t & 63, wave = t >> 6;
    int wr = wave >> 1, wc = wave & 1;
    int m0 = blockIdx.y * 64, n0 = blockIdx.x * 64;
    int lr = t >> 2, lk = (t & 3) * 8;
    int fr = lane & 15, fk = (lane >> 4) * 8;
    fx4 acc00 = {0.f, 0.f, 0.f, 0.f}, acc01 = {0.f, 0.f, 0.f, 0.f};
    fx4 acc10 = {0.f, 0.f, 0.f, 0.f}, acc11 = {0.f, 0.f, 0.f, 0.f};
    for (int k0 = 0; k0 < K; k0 += 32) {
        u16x8 av = {0, 0, 0, 0, 0, 0, 0, 0};
        u16x8 bv = {0, 0, 0, 0, 0, 0, 0, 0};
        int ar = m0 + lr;
        if (ar < M) av = *(const u16x8*)(A + (size_t)ar * K + k0 + lk);
        int br = n0 + lr;
        if (br < N) bv = *(const u16x8*)(B + (size_t)br * K + k0 + lk);
        __syncthreads();
        *(u16x8*)(&As[lr][lk]) = av;
        *(u16x8*)(&Bs[lr][lk]) = bv;
        __syncthreads();
        bfx8 a0 = *(const bfx8*)(&As[wr * 32 + fr][fk]);
        bfx8 a1 = *(const bfx8*)(&As[wr * 32 + 16 + fr][fk]);
        bfx8 b0 = *(const bfx8*)(&Bs[wc * 32 + fr][fk]);
        bfx8 b1 = *(const bfx8*)(&Bs[wc * 32 + 16 + fr][fk]);
        acc00 = __builtin_amdgcn_mfma_f32_16x16x32_bf16(a0, b0, acc00, 0, 0, 0);
        acc01 = __builtin_amdgcn_mfma_f32_16x16x32_bf16(a0, b1, acc01, 0, 0, 0);
        acc10 = __builtin_amdgcn_mfma_f32_16x16x32_bf16(a1, b0, acc10, 0, 0, 0);
        acc11 = __builtin_amdgcn_mfma_f32_16x16x32_bf16(a1, b1, acc11, 0, 0, 0);
    }
    int orow = m0 + wr * 32 + (lane >> 4) * 4;
    int ocol = n0 + wc * 32 + fr;
    #pragma unroll
    for (int i = 0; i < 4; ++i) {
        int r0 = orow + i;
        if (r0 < M) {
            if (ocol < N)      C[(size_t)r0 * N + ocol] = acc00[i];
            if (ocol + 16 < N) C[(size_t)r0 * N + ocol + 16] = acc01[i];
        }
        int r1 = orow + 16 + i;
        if (r1 < M) {
            if (ocol < N)      C[(size_t)r1 * N + ocol] = acc10[i];
            if (ocol + 16 < N) C[(size_t)r1 * N + ocol + 16] = acc11[i];
        }
    }
}

// ---------------- depthwise causal conv (width 4) + bias + SiLU ----------------
__global__ __launch_bounds__(256) void k_conv(const float* __restrict__ zx,
                                              const float* __restrict__ cw,
                                              const float* __restrict__ cb,
                                              float* __restrict__ xbc) {
    int idx = blockIdx.x * 256 + threadIdx.x;
    if (idx >= TOKENS * CONVDIM) return;
    int row = idx / CONVDIM;
    int col = idx - row * CONVDIM;
    int l = row % SEQL;
    float acc = cb[col];
    #pragma unroll
    for (int j = 0; j < 4; ++j) {
        int lj = l - 3 + j;
        if (lj >= 0)
            acc += zx[(size_t)(row - 3 + j) * NPROJ + DINNER + col] * cw[col * 4 + j];
    }
    xbc[idx] = acc / (1.f + expf(-acc));
}

// ---------------- phase 1: per-group (5-chunk) local scan ----------------
// grid: BATCHN*NHEADS*GROUPS blocks, 256 threads. Writes group-local Y into
// ybuf, group-final state into Sg, group total log-decay into Tg, and
// group-relative cumulative log-decay per token into cumA.
__global__ __launch_bounds__(256) void k_scan1(const float* __restrict__ xbc,
                                               const float* __restrict__ dtv,
                                               const float* __restrict__ A_log,
                                               float* __restrict__ ybuf,
                                               float* __restrict__ Sg,
                                               float* __restrict__ Tg,
                                               float* __restrict__ cumA) {
    int bid = blockIdx.x;
    int b = bid / (NHEADS * GROUPS);
    int r = bid % (NHEADS * GROUPS);
    int h = r / GROUPS, g = r % GROUPS;
    float A = -expf(A_log[h]);
    int t = threadIdx.x;
    int p = t & 63, nq = t >> 6, n0 = nq * 32;
    float S[32];
    #pragma unroll
    for (int i = 0; i < 32; ++i) S[i] = 0.f;
    __shared__ float sB[10][128], sC[10][128], sx[10][64], sdt[10];
    __shared__ float part[10][64][5];
    float groupA = 0.f;
    for (int c5 = 0; c5 < GCH; ++c5) {
        int c = g * GCH + c5;
        int tok0 = b * SEQL + c * CHUNKL;
        for (int i = t; i < 1280; i += 256) {
            int l = i >> 7, n = i & 127;
            sB[l][n] = xbc[(size_t)(tok0 + l) * CONVDIM + DINNER + n];
            sC[l][n] = xbc[(size_t)(tok0 + l) * CONVDIM + DINNER + DSTATE + n];
        }
        for (int i = t; i < 640; i += 256) {
            int l = i >> 6, pp = i & 63;
            sx[l][pp] = xbc[(size_t)(tok0 + l) * CONVDIM + h * 64 + pp];
        }
        if (t < 10) sdt[t] = dtv[(size_t)(tok0 + t) * NHEADS + h];
        __syncthreads();
        float Acs[10];
        float run = 0.f;
        #pragma unroll
        for (int l = 0; l < 10; ++l) { run += A * sdt[l]; Acs[l] = run; }
        float csum = run;
        if (t < 10) cumA[((size_t)(b * NHEADS + h)) * SEQL + c * CHUNKL + t] = groupA + Acs[t];
        // Y_off partial from current state
        #pragma unroll
        for (int l = 0; l < 10; ++l) {
            float acc = 0.f;
            const float4* cp = (const float4*)&sC[l][n0];
            #pragma unroll
            for (int i = 0; i < 8; ++i) {
                float4 cv = cp[i];
                acc += cv.x * S[i * 4] + cv.y * S[i * 4 + 1] + cv.z * S[i * 4 + 2] + cv.w * S[i * 4 + 3];
            }
            part[l][p][nq] = acc;
        }
        __syncthreads();
        for (int i = t; i < 640; i += 256) {
            int l = i >> 6, pp = i & 63;
            float v = (part[l][pp][0] + part[l][pp][1] + part[l][pp][2] + part[l][pp][3]) * expf(Acs[l]);
            ybuf[(size_t)(tok0 + l) * DINNER + h * 64 + pp] = v;
        }
        // state update
        float a[10];
        #pragma unroll
        for (int l = 0; l < 10; ++l) a[l] = sx[l][p] * sdt[l] * expf(csum - Acs[l]);
        float cs = expf(csum);
        #pragma unroll
        for (int i = 0; i < 32; i += 4) {
            float v0 = S[i] * cs, v1 = S[i + 1] * cs, v2 = S[i + 2] * cs, v3 = S[i + 3] * cs;
            #pragma unroll
            for (int l = 0; l < 10; ++l) {
                float4 bv = *(const float4*)&sB[l][n0 + i];
                v0 += a[l] * bv.x; v1 += a[l] * bv.y; v2 += a[l] * bv.z; v3 += a[l] * bv.w;
            }
            S[i] = v0; S[i + 1] = v1; S[i + 2] = v2; S[i + 3] = v3;
        }
        groupA += csum;
        __syncthreads();
    }
    size_t base = ((size_t)((b * NHEADS + h) * GROUPS + g)) * 8192 + (size_t)p * 128 + n0;
    #pragma unroll
    for (int i = 0; i < 32; i += 4) {
        float4 v; v.x = S[i]; v.y = S[i + 1]; v.z = S[i + 2]; v.w = S[i + 3];
        *(float4*)&Sg[base + i] = v;
    }
    if (t == 0) Tg[(b * NHEADS + h) * GROUPS + g] = groupA;
}

// ---------------- phase 2: 20-step scan over group boundary states (in place) ----
// Sg[g] on входе = group-local final states; on exit = incoming state S_in[g].
__global__ __launch_bounds__(256) void k_scan2(float* __restrict__ Sg,
                                               const float* __restrict__ Tg) {
    int bid = blockIdx.x;          // 64*32 blocks
    int bh = bid >> 5, sub = bid & 31;
    int e = sub * 256 + threadIdx.x;   // 0..8191
    __shared__ float sT[GROUPS];
    if (threadIdx.x < GROUPS) sT[threadIdx.x] = Tg[bh * GROUPS + threadIdx.x];
    __syncthreads();
    float S = 0.f;
    size_t base = (size_t)bh * GROUPS * 8192 + e;
    for (int g = 0; g < GROUPS; ++g) {
        size_t off = base + (size_t)g * 8192;
        float sg = Sg[off];
        Sg[off] = S;
        S = expf(sT[g]) * S + sg;
    }
}

// ---------------- phase 3: add cross-group Y correction ----------------
__global__ __launch_bounds__(256) void k_scan3(const float* __restrict__ xbc,
                                               const float* __restrict__ Sg,   // = S_in
                                               const float* __restrict__ cumA,
                                               float* __restrict__ ybuf) {
    int bid = blockIdx.x;
    int b = bid / (NHEADS * GROUPS);
    int r = bid % (NHEADS * GROUPS);
    int h = r / GROUPS, g = r % GROUPS;
    if (g == 0) return;   // incoming state is zero
    int t = threadIdx.x;
    int p = t & 63, nq = t >> 6, n0 = nq * 32;
    float S[32];
    size_t base = ((size_t)((b * NHEADS + h) * GROUPS + g)) * 8192 + (size_t)p * 128 + n0;
    #pragma unroll
    for (int i = 0; i < 32; i += 4) {
        float4 v = *(const float4*)&Sg[base + i];
        S[i] = v.x; S[i + 1] = v.y; S[i + 2] = v.z; S[i + 3] = v.w;
    }
    __shared__ float sC[10][128], sE[10];
    __shared__ float part[10][64][5];
    for (int c5 = 0; c5 < GCH; ++c5) {
        int c = g * GCH + c5;
        int tok0 = b * SEQL + c * CHUNKL;
        for (int i = t; i < 1280; i += 256) {
            int l = i >> 7, n = i & 127;
            sC[l][n] = xbc[(size_t)(tok0 + l) * CONVDIM + DINNER + DSTATE + n];
        }
        if (t < 10) sE[t] = expf(cumA[((size_t)(b * NHEADS + h)) * SEQL + c * CHUNKL + t]);
        __syncthreads();
        #pragma unroll
        for (int l = 0; l < 10; ++l) {
            float acc = 0.f;
            const float4* cp = (const float4*)&sC[l][n0];
            #pragma unroll
            for (int i = 0; i < 8; ++i) {
                float4 cv = cp[i];
                acc += cv.x * S[i * 4] + cv.y * S[i * 4 + 1] + cv.z * S[i * 4 + 2] + cv.w * S[i * 4 + 3];
            }
            part[l][p][nq] = acc;
        }
        __syncthreads();
        for (int i = t; i < 640; i += 256) {
            int l = i >> 6, pp = i & 63;
            size_t off = (size_t)(tok0 + l) * DINNER + h * 64 + pp;
            ybuf[off] += (part[l][pp][0] + part[l][pp][1] + part[l][pp][2] + part[l][pp][3]) * sE[l];
        }
        __syncthreads();
    }
}

// ---------------- per-chunk diagonal block + D*x, added into ybuf ----------------
__global__ __launch_bounds__(256) void k_diag(const float* __restrict__ xbc,
                                              const float* __restrict__ dtv,
                                              const float* __restrict__ A_log,
                                              const float* __restrict__ Dp,
                                              float* __restrict__ ybuf) {
    int bc = blockIdx.x >> 2;
    int hg = blockIdx.x & 3;
    int b = bc / NCHUNK, c = bc - b * NCHUNK;
    int tok0 = b * SEQL + c * CHUNKL;
    int t = threadIdx.x;
    __shared__ float sB[10][128], sC[10][128], sxr[10][512];
    __shared__ float sdt[10][8], sdA[10][8];
    __shared__ float sG[10][10], sW[10][10];
    for (int i = t; i < 1280; i += 256) {
        int l = i >> 7, n = i & 127;
        sB[l][n] = xbc[(size_t)(tok0 + l) * CONVDIM + DINNER + n];
        sC[l][n] = xbc[(size_t)(tok0 + l) * CONVDIM + DINNER + DSTATE + n];
    }
    for (int i = t; i < 5120; i += 256) {
        int l = i >> 9, q = i & 511;
        sxr[l][q] = xbc[(size_t)(tok0 + l) * CONVDIM + hg * 512 + q];
    }
    if (t < 80) {
        int l = t >> 3, hh = t & 7;
        int h = hg * 8 + hh;
        float d = dtv[(size_t)(tok0 + l) * NHEADS + h];
        sdt[l][hh] = d;
        sdA[l][hh] = -expf(A_log[h]) * d;
    }
    __syncthreads();
    if (t < 100) {
        int l = t / 10, s = t - (t / 10) * 10;
        float acc = 0.f;
        for (int n = 0; n < 128; ++n) acc += sC[l][n] * sB[s][n];
        sG[l][s] = acc;
    }
    __syncthreads();
    for (int hh = 0; hh < 8; ++hh) {
        int h = hg * 8 + hh;
        if (t < 100) {
            int l = t / 10, s = t - (t / 10) * 10;
            if (s <= l) {
                float cum = 0.f;
                for (int k = s + 1; k <= l; ++k) cum += sdA[k][hh];
                sW[l][s] = sG[l][s] * expf(cum);
            } else {
                sW[l][s] = 0.f;
            }
        }
        __syncthreads();
        float Dh = Dp[h];
        for (int i = t; i < 640; i += 256) {
            int l = i >> 6, pp = i & 63;
            float acc = 0.f;
            for (int s = 0; s <= l; ++s) acc += sW[l][s] * sxr[s][hh * 64 + pp] * sdt[s][hh];
            size_t off = (size_t)(tok0 + l) * DINNER + h * 64 + pp;
            ybuf[off] = ybuf[off] + acc + Dh * sxr[l][hh * 64 + pp];
        }
        __syncthreads();
    }
}

// ---------------- gate (y * silu(z)) + RMSNorm + norm_w, output bf16 ----------------
__global__ __launch_bounds__(256) void k_norm(const float* __restrict__ ybuf,
                                              const float* __restrict__ zx,
                                              const float* __restrict__ normw,
                                              unsigned short* __restrict__ ynb) {
    int row = blockIdx.x;
    int t = threadIdx.x;
    float v[8];
    float ss = 0.f;
    #pragma unroll
    for (int j = 0; j < 8; ++j) {
        int col = t + j * 256;
        float y = ybuf[(size_t)row * DINNER + col];
        float z = zx[(size_t)row * NPROJ + col];
        y *= z / (1.f + expf(-z));
        v[j] = y;
        ss += y * y;
    }
    #pragma unroll
    for (int off = 32; off > 0; off >>= 1) ss += __shfl_down(ss, off, 64);
    __shared__ float red[4];
    int lane = t & 63, wv = t >> 6;
    if (lane == 0) red[wv] = ss;
    __syncthreads();
    float tot = red[0] + red[1] + red[2] + red[3];
    float r = rsqrtf(tot * (1.f / DINNER) + 1e-5f);
    #pragma unroll
    for (int j = 0; j < 8; ++j) {
        int col = t + j * 256;
        ynb[(size_t)row * DINNER + col] = f2bf(v[j] * r * normw[col]);
    }
}

extern "C" void kernel_launch(void* const* d_in, const int* in_sizes, int n_in,
                              void* d_out, int out_size, void* d_ws, size_t ws_size,
                              hipStream_t stream) {
    const float* x       = (const float*)d_in[0];
    const float* W_in    = (const float*)d_in[1];
    const float* conv_w  = (const float*)d_in[2];
    const float* conv_b  = (const float*)d_in[3];
    const float* dt_bias = (const float*)d_in[4];
    const float* A_log   = (const float*)d_in[5];
    const float* Dp      = (const float*)d_in[6];
    const float* norm_w  = (const float*)d_in[7];
    const float* W_out   = (const float*)d_in[8];
    float* out = (float*)d_out;

    char* w = (char*)d_ws;
    auto alloc = [&](size_t bytes) {
        char* p = w;
        w += (bytes + 255) & ~(size_t)255;
        return p;
    };
    unsigned short* xb    = (unsigned short*)alloc((size_t)TOKENS * DMODEL * 2);
    unsigned short* winb  = (unsigned short*)alloc((size_t)NPROJ * DMODEL * 2);
    unsigned short* woutb = (unsigned short*)alloc((size_t)DMODEL * DINNER * 2);
    float* zx   = (float*)alloc((size_t)TOKENS * NPROJ * 4);
    float* xbc  = (float*)alloc((size_t)TOKENS * CONVDIM * 4);
    float* dtv  = (float*)alloc((size_t)TOKENS * NHEADS * 4);
    float* yb   = (float*)alloc((size_t)TOKENS * DINNER * 4);
    unsigned short* ynb = (unsigned short*)alloc((size_t)TOKENS * DINNER * 2);
    float* SgB  = (float*)alloc((size_t)BATCHN * NHEADS * GROUPS * HEADDIM * DSTATE * 4);
    float* TgB  = (float*)alloc((size_t)BATCHN * NHEADS * GROUPS * 4);
    float* cumA = (float*)alloc((size_t)BATCHN * NHEADS * SEQL * 4);

    k_f2bf<<<(TOKENS * DMODEL / 4 + 255) / 256, 256, 0, stream>>>(x, xb, TOKENS * DMODEL / 4);
    k_f2bf<<<(NPROJ * DMODEL / 4 + 255) / 256, 256, 0, stream>>>(W_in, winb, NPROJ * DMODEL / 4);
    k_f2bf<<<(DMODEL * DINNER / 4 + 255) / 256, 256, 0, stream>>>(W_out, woutb, DMODEL * DINNER / 4);
    k_dt<<<(TOKENS * NHEADS + 255) / 256, 256, 0, stream>>>(x, W_in, dt_bias, dtv);
    dim3 g1((NPROJ + 63) / 64, (TOKENS + 63) / 64);
    k_gemm_nt<<<g1, 256, 0, stream>>>(xb, winb, zx, TOKENS, NPROJ, DMODEL);
    k_conv<<<(TOKENS * CONVDIM + 255) / 256, 256, 0, stream>>>(zx, conv_w, conv_b, xbc);
    k_scan1<<<BATCHN * NHEADS * GROUPS, 256, 0, stream>>>(xbc, dtv, A_log, yb, SgB, TgB, cumA);
    k_scan2<<<BATCHN * NHEADS * 32, 256, 0, stream>>>(SgB, TgB);
    k_scan3<<<BATCHN * NHEADS * GROUPS, 256, 0, stream>>>(xbc, SgB, cumA, yb);
    k_diag<<<BATCHN * NCHUNK * 4, 256, 0, stream>>>(xbc, dtv, A_log, Dp, yb);
    k_norm<<<TOKENS, 256, 0, stream>>>(yb, zx, norm_w, ynb);
    dim3 g2((DMODEL + 63) / 64, (TOKENS + 63) / 64);
    k_gemm_nt<<<g2, 256, 0, stream>>>(ynb, woutb, out, TOKENS, DMODEL, DINNER);
}

// Round 3
// 321.703 us; speedup vs baseline: 2.4033x; 1.0099x over previous
//
#include <hip/hip_runtime.h>
#include <hip/hip_bf16.h>

#define BATCHN 2
#define SEQL 1000
#define DMODEL 1024
#define DSTATE 128
#define HEADDIM 64
#define CHUNKL 10
#define DINNER 2048
#define NHEADS 32
#define CONVDIM 2304   // DINNER + 2*DSTATE
#define NPROJ 4384     // 2*DINNER + 2*DSTATE + NHEADS
#define TOKENS 2000
#define NCHUNK 100
#define GROUPS 20      // groups per sequence
#define GCH 5          // chunks per group
#define MPAD 2048      // tokens padded to 128 multiple
#define NPAD1 4480     // NPROJ padded to 128 multiple

typedef __bf16 bfx8 __attribute__((ext_vector_type(8)));
typedef float fx4 __attribute__((ext_vector_type(4)));
typedef unsigned short u16x8 __attribute__((ext_vector_type(8)));

__device__ __forceinline__ unsigned short f2bf(float f) {
    unsigned int u = __builtin_bit_cast(unsigned int, f);
    u += 0x7FFFu + ((u >> 16) & 1u);
    return (unsigned short)(u >> 16);
}

__device__ __forceinline__ void gload16(const void* g, void* l) {
    __builtin_amdgcn_global_load_lds(
        (const __attribute__((address_space(1))) void*)g,
        (__attribute__((address_space(3))) void*)l, 16, 0, 0);
}

// ---------------- fp32 -> bf16 conversion with zero padding ----------------
__global__ __launch_bounds__(256) void k_f2bf_pad(const float* __restrict__ src,
                                                  unsigned short* __restrict__ dst,
                                                  int n4src, int n4dst) {
    int i = blockIdx.x * 256 + threadIdx.x;
    if (i >= n4dst) return;
    ushort4 o = {0, 0, 0, 0};
    if (i < n4src) {
        float4 v = ((const float4*)src)[i];
        o.x = f2bf(v.x); o.y = f2bf(v.y); o.z = f2bf(v.z); o.w = f2bf(v.w);
    }
    ((ushort4*)dst)[i] = o;
}

// ---------------- dt head projection in fp32 (exp-sensitive path) ----------------
// one block per 8 tokens; x rows staged in LDS; thread = (token, head)
__global__ __launch_bounds__(256) void k_dt(const float* __restrict__ x,
                                            const float* __restrict__ win,
                                            const float* __restrict__ dt_bias,
                                            float* __restrict__ dtv) {
    __shared__ float sx[8][1024];
    int t = threadIdx.x;
    int tok0 = blockIdx.x * 8;
    for (int i = t; i < 8 * 256; i += 256) {
        int tok = i >> 8, k4 = i & 255;
        ((float4*)&sx[tok][0])[k4] = ((const float4*)(x + (size_t)(tok0 + tok) * DMODEL))[k4];
    }
    __syncthreads();
    int tl = t >> 5, h = t & 31;
    const float4* wr_ = (const float4*)(win + (size_t)(2 * DINNER + 2 * DSTATE + h) * DMODEL);
    const float4* xr = (const float4*)&sx[tl][0];
    float acc = 0.f;
    #pragma unroll 4
    for (int k = 0; k < 256; ++k) {
        float4 a = xr[k], b = wr_[k];
        acc += a.x * b.x + a.y * b.y + a.z * b.z + a.w * b.w;
    }
    float v = acc + dt_bias[h];
    dtv[(size_t)(tok0 + tl) * NHEADS + h] = fmaxf(v, 0.f) + log1pf(expf(-fabsf(v)));
}

// ---------------- bf16 NT GEMM (m97 structure): C[M][N] = A[M][K] * B[N][K]^T ----
// 128x128 tile, BK=32, 4 waves (2x2), each wave 4x4 frags of 16x16x32.
// A has >= gridDim.y*128 rows, B has >= gridDim.x*128 rows (zero padded).
__global__ __launch_bounds__(256) void k_gemm128(const unsigned short* __restrict__ A,
                                                 const unsigned short* __restrict__ B,
                                                 float* __restrict__ C,
                                                 int Mstore, int N, int K) {
    __shared__ __attribute__((aligned(16))) unsigned short As[4096];  // 128 x 32
    __shared__ __attribute__((aligned(16))) unsigned short Bs[4096];
    int t = threadIdx.x;
    int lane = t & 63, wave = t >> 6;
    int wr = wave >> 1, wc = wave & 1;
    int m0 = blockIdx.y * 128, n0 = blockIdx.x * 128;
    int fr = lane & 15, fk = (lane >> 4) * 8;
    fx4 acc[4][4] = {};
    const unsigned short* Ag = A + (size_t)(m0 + (t >> 2)) * K + (t & 3) * 8;
    const unsigned short* Bg = B + (size_t)(n0 + (t >> 2)) * K + (t & 3) * 8;
    for (int k0 = 0; k0 < K; k0 += 32) {
        __syncthreads();
        gload16(Ag + k0, As + t * 8);
        gload16(Ag + (size_t)64 * K + k0, As + 2048 + t * 8);
        gload16(Bg + k0, Bs + t * 8);
        gload16(Bg + (size_t)64 * K + k0, Bs + 2048 + t * 8);
        __syncthreads();
        bfx8 a[4], b[4];
        #pragma unroll
        for (int m = 0; m < 4; ++m) a[m] = *(const bfx8*)&As[(wr * 64 + m * 16 + fr) * 32 + fk];
        #pragma unroll
        for (int n = 0; n < 4; ++n) b[n] = *(const bfx8*)&Bs[(wc * 64 + n * 16 + fr) * 32 + fk];
        #pragma unroll
        for (int m = 0; m < 4; ++m)
            #pragma unroll
            for (int n = 0; n < 4; ++n)
                acc[m][n] = __builtin_amdgcn_mfma_f32_16x16x32_bf16(a[m], b[n], acc[m][n], 0, 0, 0);
    }
    #pragma unroll
    for (int m = 0; m < 4; ++m) {
        int rbase = m0 + wr * 64 + m * 16 + (lane >> 4) * 4;
        #pragma unroll
        for (int i = 0; i < 4; ++i) {
            int r = rbase + i;
            if (r < Mstore) {
                #pragma unroll
                for (int n = 0; n < 4; ++n) {
                    int c = n0 + wc * 64 + n * 16 + fr;
                    if (c < N) C[(size_t)r * N + c] = acc[m][n][i];
                }
            }
        }
    }
}

// ---------------- depthwise causal conv (width 4) + bias + SiLU ----------------
__global__ __launch_bounds__(256) void k_conv(const float* __restrict__ zx,
                                              const float* __restrict__ cw,
                                              const float* __restrict__ cb,
                                              float* __restrict__ xbc) {
    int idx = blockIdx.x * 256 + threadIdx.x;
    if (idx >= TOKENS * CONVDIM) return;
    int row = idx / CONVDIM;
    int col = idx - row * CONVDIM;
    int l = row % SEQL;
    float acc = cb[col];
    #pragma unroll
    for (int j = 0; j < 4; ++j) {
        int lj = l - 3 + j;
        if (lj >= 0)
            acc += zx[(size_t)(row - 3 + j) * NPROJ + DINNER + col] * cw[col * 4 + j];
    }
    xbc[idx] = acc / (1.f + expf(-acc));
}

// ---------------- phase 1: per-group (5-chunk) local scan, 512 threads ----------
__global__ __launch_bounds__(512) void k_scan1(const float* __restrict__ xbc,
                                               const float* __restrict__ dtv,
                                               const float* __restrict__ A_log,
                                               float* __restrict__ ybuf,
                                               float* __restrict__ Sg,
                                               float* __restrict__ Tg,
                                               float* __restrict__ cumA) {
    int bid = blockIdx.x;
    int b = bid / (NHEADS * GROUPS);
    int r = bid % (NHEADS * GROUPS);
    int h = r / GROUPS, g = r % GROUPS;
    float A = -expf(A_log[h]);
    int t = threadIdx.x;
    int p = t & 63, nq = t >> 6, n0 = nq * 16;
    float S[16];
    #pragma unroll
    for (int i = 0; i < 16; ++i) S[i] = 0.f;
    __shared__ float sB[10][128], sC[10][128], sx[10][64], sdt[10];
    __shared__ float part[10][8][64];
    float groupA = 0.f;
    for (int c5 = 0; c5 < GCH; ++c5) {
        int c = g * GCH + c5;
        int tok0 = b * SEQL + c * CHUNKL;
        for (int i = t; i < 1280; i += 512) {
            int l = i >> 7, n = i & 127;
            sB[l][n] = xbc[(size_t)(tok0 + l) * CONVDIM + DINNER + n];
            sC[l][n] = xbc[(size_t)(tok0 + l) * CONVDIM + DINNER + DSTATE + n];
        }
        for (int i = t; i < 640; i += 512) {
            int l = i >> 6, pp = i & 63;
            sx[l][pp] = xbc[(size_t)(tok0 + l) * CONVDIM + h * 64 + pp];
        }
        if (t < 10) sdt[t] = dtv[(size_t)(tok0 + t) * NHEADS + h];
        __syncthreads();
        float Acs[10];
        float run = 0.f;
        #pragma unroll
        for (int l = 0; l < 10; ++l) { run += A * sdt[l]; Acs[l] = run; }
        float csum = run;
        if (t < 10) cumA[((size_t)(b * NHEADS + h)) * SEQL + c * CHUNKL + t] = groupA + Acs[t];
        #pragma unroll
        for (int l = 0; l < 10; ++l) {
            float acc = 0.f;
            const float4* cp = (const float4*)&sC[l][n0];
            #pragma unroll
            for (int i = 0; i < 4; ++i) {
                float4 cv = cp[i];
                acc += cv.x * S[i * 4] + cv.y * S[i * 4 + 1] + cv.z * S[i * 4 + 2] + cv.w * S[i * 4 + 3];
            }
            part[l][nq][p] = acc;
        }
        __syncthreads();
        for (int i = t; i < 640; i += 512) {
            int l = i >> 6, pp = i & 63;
            float v = 0.f;
            #pragma unroll
            for (int j = 0; j < 8; ++j) v += part[l][j][pp];
            ybuf[(size_t)(tok0 + l) * DINNER + h * 64 + pp] = v * expf(Acs[l]);
        }
        float a[10];
        #pragma unroll
        for (int l = 0; l < 10; ++l) a[l] = sx[l][p] * sdt[l] * expf(csum - Acs[l]);
        float cs = expf(csum);
        #pragma unroll
        for (int i = 0; i < 16; i += 4) {
            float v0 = S[i] * cs, v1 = S[i + 1] * cs, v2 = S[i + 2] * cs, v3 = S[i + 3] * cs;
            #pragma unroll
            for (int l = 0; l < 10; ++l) {
                float4 bv = *(const float4*)&sB[l][n0 + i];
                v0 += a[l] * bv.x; v1 += a[l] * bv.y; v2 += a[l] * bv.z; v3 += a[l] * bv.w;
            }
            S[i] = v0; S[i + 1] = v1; S[i + 2] = v2; S[i + 3] = v3;
        }
        groupA += csum;
        __syncthreads();
    }
    size_t base = ((size_t)((b * NHEADS + h) * GROUPS + g)) * 8192 + (size_t)p * 128 + n0;
    #pragma unroll
    for (int i = 0; i < 16; i += 4) {
        float4 v; v.x = S[i]; v.y = S[i + 1]; v.z = S[i + 2]; v.w = S[i + 3];
        *(float4*)&Sg[base + i] = v;
    }
    if (t == 0) Tg[(b * NHEADS + h) * GROUPS + g] = groupA;
}

// ---------------- phase 2: 20-step scan over group boundary states (in place) ----
__global__ __launch_bounds__(256) void k_scan2(float* __restrict__ Sg,
                                               const float* __restrict__ Tg) {
    int bid = blockIdx.x;          // 64*32 blocks
    int bh = bid >> 5, sub = bid & 31;
    int e = sub * 256 + threadIdx.x;   // 0..8191
    __shared__ float sT[GROUPS];
    if (threadIdx.x < GROUPS) sT[threadIdx.x] = Tg[bh * GROUPS + threadIdx.x];
    __syncthreads();
    float S = 0.f;
    size_t base = (size_t)bh * GROUPS * 8192 + e;
    for (int g = 0; g < GROUPS; ++g) {
        size_t off = base + (size_t)g * 8192;
        float sg = Sg[off];
        Sg[off] = S;
        S = expf(sT[g]) * S + sg;
    }
}

// ---------------- phase 3: add cross-group Y correction, 512 threads ----------
__global__ __launch_bounds__(512) void k_scan3(const float* __restrict__ xbc,
                                               const float* __restrict__ Sg,   // = S_in
                                               const float* __restrict__ cumA,
                                               float* __restrict__ ybuf) {
    int bid = blockIdx.x;
    int b = bid / (NHEADS * GROUPS);
    int r = bid % (NHEADS * GROUPS);
    int h = r / GROUPS, g = r % GROUPS;
    if (g == 0) return;
    int t = threadIdx.x;
    int p = t & 63, nq = t >> 6, n0 = nq * 16;
    float S[16];
    size_t base = ((size_t)((b * NHEADS + h) * GROUPS + g)) * 8192 + (size_t)p * 128 + n0;
    #pragma unroll
    for (int i = 0; i < 16; i += 4) {
        float4 v = *(const float4*)&Sg[base + i];
        S[i] = v.x; S[i + 1] = v.y; S[i + 2] = v.z; S[i + 3] = v.w;
    }
    __shared__ float sC[10][128], sE[10];
    __shared__ float part[10][8][64];
    for (int c5 = 0; c5 < GCH; ++c5) {
        int c = g * GCH + c5;
        int tok0 = b * SEQL + c * CHUNKL;
        for (int i = t; i < 1280; i += 512) {
            int l = i >> 7, n = i & 127;
            sC[l][n] = xbc[(size_t)(tok0 + l) * CONVDIM + DINNER + DSTATE + n];
        }
        if (t < 10) sE[t] = expf(cumA[((size_t)(b * NHEADS + h)) * SEQL + c * CHUNKL + t]);
        __syncthreads();
        #pragma unroll
        for (int l = 0; l < 10; ++l) {
            float acc = 0.f;
            const float4* cp = (const float4*)&sC[l][n0];
            #pragma unroll
            for (int i = 0; i < 4; ++i) {
                float4 cv = cp[i];
                acc += cv.x * S[i * 4] + cv.y * S[i * 4 + 1] + cv.z * S[i * 4 + 2] + cv.w * S[i * 4 + 3];
            }
            part[l][nq][p] = acc;
        }
        __syncthreads();
        for (int i = t; i < 640; i += 512) {
            int l = i >> 6, pp = i & 63;
            float v = 0.f;
            #pragma unroll
            for (int j = 0; j < 8; ++j) v += part[l][j][pp];
            size_t off = (size_t)(tok0 + l) * DINNER + h * 64 + pp;
            ybuf[off] += v * sE[l];
        }
        __syncthreads();
    }
}

// ---------------- per-chunk diagonal block + D*x, added into ybuf ----------------
__global__ __launch_bounds__(256) void k_diag(const float* __restrict__ xbc,
                                              const float* __restrict__ dtv,
                                              const float* __restrict__ A_log,
                                              const float* __restrict__ Dp,
                                              float* __restrict__ ybuf) {
    int bc = blockIdx.x >> 2;
    int hg = blockIdx.x & 3;
    int b = bc / NCHUNK, c = bc - b * NCHUNK;
    int tok0 = b * SEQL + c * CHUNKL;
    int t = threadIdx.x;
    __shared__ float sB[10][128], sC[10][128], sxr[10][512];
    __shared__ float sdt[10][8], sdA[10][8];
    __shared__ float sG[10][10], sW[10][10];
    for (int i = t; i < 1280; i += 256) {
        int l = i >> 7, n = i & 127;
        sB[l][n] = xbc[(size_t)(tok0 + l) * CONVDIM + DINNER + n];
        sC[l][n] = xbc[(size_t)(tok0 + l) * CONVDIM + DINNER + DSTATE + n];
    }
    for (int i = t; i < 5120; i += 256) {
        int l = i >> 9, q = i & 511;
        sxr[l][q] = xbc[(size_t)(tok0 + l) * CONVDIM + hg * 512 + q];
    }
    if (t < 80) {
        int l = t >> 3, hh = t & 7;
        int h = hg * 8 + hh;
        float d = dtv[(size_t)(tok0 + l) * NHEADS + h];
        sdt[l][hh] = d;
        sdA[l][hh] = -expf(A_log[h]) * d;
    }
    __syncthreads();
    if (t < 100) {
        int l = t / 10, s = t - (t / 10) * 10;
        float acc = 0.f;
        for (int n = 0; n < 128; ++n) acc += sC[l][n] * sB[s][n];
        sG[l][s] = acc;
    }
    __syncthreads();
    for (int hh = 0; hh < 8; ++hh) {
        int h = hg * 8 + hh;
        if (t < 100) {
            int l = t / 10, s = t - (t / 10) * 10;
            if (s <= l) {
                float cum = 0.f;
                for (int k = s + 1; k <= l; ++k) cum += sdA[k][hh];
                sW[l][s] = sG[l][s] * expf(cum);
            } else {
                sW[l][s] = 0.f;
            }
        }
        __syncthreads();
        float Dh = Dp[h];
        for (int i = t; i < 640; i += 256) {
            int l = i >> 6, pp = i & 63;
            float acc = 0.f;
            for (int s = 0; s <= l; ++s) acc += sW[l][s] * sxr[s][hh * 64 + pp] * sdt[s][hh];
            size_t off = (size_t)(tok0 + l) * DINNER + h * 64 + pp;
            ybuf[off] = ybuf[off] + acc + Dh * sxr[l][hh * 64 + pp];
        }
        __syncthreads();
    }
}

// ---------------- gate (y * silu(z)) + RMSNorm + norm_w, output bf16 (padded) ----
__global__ __launch_bounds__(256) void k_norm(const float* __restrict__ ybuf,
                                              const float* __restrict__ zx,
                                              const float* __restrict__ normw,
                                              unsigned short* __restrict__ ynb) {
    int row = blockIdx.x;
    int t = threadIdx.x;
    if (row >= TOKENS) {
        #pragma unroll
        for (int j = 0; j < 8; ++j) ynb[(size_t)row * DINNER + t + j * 256] = 0;
        return;
    }
    float v[8];
    float ss = 0.f;
    #pragma unroll
    for (int j = 0; j < 8; ++j) {
        int col = t + j * 256;
        float y = ybuf[(size_t)row * DINNER + col];
        float z = zx[(size_t)row * NPROJ + col];
        y *= z / (1.f + expf(-z));
        v[j] = y;
        ss += y * y;
    }
    #pragma unroll
    for (int off = 32; off > 0; off >>= 1) ss += __shfl_down(ss, off, 64);
    __shared__ float red[4];
    int lane = t & 63, wv = t >> 6;
    if (lane == 0) red[wv] = ss;
    __syncthreads();
    float tot = red[0] + red[1] + red[2] + red[3];
    float r = rsqrtf(tot * (1.f / DINNER) + 1e-5f);
    #pragma unroll
    for (int j = 0; j < 8; ++j) {
        int col = t + j * 256;
        ynb[(size_t)row * DINNER + col] = f2bf(v[j] * r * normw[col]);
    }
}

extern "C" void kernel_launch(void* const* d_in, const int* in_sizes, int n_in,
                              void* d_out, int out_size, void* d_ws, size_t ws_size,
                              hipStream_t stream) {
    const float* x       = (const float*)d_in[0];
    const float* W_in    = (const float*)d_in[1];
    const float* conv_w  = (const float*)d_in[2];
    const float* conv_b  = (const float*)d_in[3];
    const float* dt_bias = (const float*)d_in[4];
    const float* A_log   = (const float*)d_in[5];
    const float* Dp      = (const float*)d_in[6];
    const float* norm_w  = (const float*)d_in[7];
    const float* W_out   = (const float*)d_in[8];
    float* out = (float*)d_out;

    char* w = (char*)d_ws;
    auto alloc = [&](size_t bytes) {
        char* p = w;
        w += (bytes + 255) & ~(size_t)255;
        return p;
    };
    unsigned short* xb    = (unsigned short*)alloc((size_t)MPAD * DMODEL * 2);
    unsigned short* winb  = (unsigned short*)alloc((size_t)NPAD1 * DMODEL * 2);
    unsigned short* woutb = (unsigned short*)alloc((size_t)DMODEL * DINNER * 2);
    float* zx   = (float*)alloc((size_t)TOKENS * NPROJ * 4);
    float* xbc  = (float*)alloc((size_t)TOKENS * CONVDIM * 4);
    float* dtv  = (float*)alloc((size_t)TOKENS * NHEADS * 4);
    float* yb   = (float*)alloc((size_t)TOKENS * DINNER * 4);
    unsigned short* ynb = (unsigned short*)alloc((size_t)MPAD * DINNER * 2);
    float* SgB  = (float*)alloc((size_t)BATCHN * NHEADS * GROUPS * HEADDIM * DSTATE * 4);
    float* TgB  = (float*)alloc((size_t)BATCHN * NHEADS * GROUPS * 4);
    float* cumA = (float*)alloc((size_t)BATCHN * NHEADS * SEQL * 4);

    int n4;
    n4 = MPAD * DMODEL / 4;
    k_f2bf_pad<<<(n4 + 255) / 256, 256, 0, stream>>>(x, xb, TOKENS * DMODEL / 4, n4);
    n4 = NPAD1 * DMODEL / 4;
    k_f2bf_pad<<<(n4 + 255) / 256, 256, 0, stream>>>(W_in, winb, NPROJ * DMODEL / 4, n4);
    n4 = DMODEL * DINNER / 4;
    k_f2bf_pad<<<(n4 + 255) / 256, 256, 0, stream>>>(W_out, woutb, n4, n4);
    k_dt<<<TOKENS / 8, 256, 0, stream>>>(x, W_in, dt_bias, dtv);
    dim3 g1(NPAD1 / 128, MPAD / 128);
    k_gemm128<<<g1, 256, 0, stream>>>(xb, winb, zx, TOKENS, NPROJ, DMODEL);
    k_conv<<<(TOKENS * CONVDIM + 255) / 256, 256, 0, stream>>>(zx, conv_w, conv_b, xbc);
    k_scan1<<<BATCHN * NHEADS * GROUPS, 512, 0, stream>>>(xbc, dtv, A_log, yb, SgB, TgB, cumA);
    k_scan2<<<BATCHN * NHEADS * 32, 256, 0, stream>>>(SgB, TgB);
    k_scan3<<<BATCHN * NHEADS * GROUPS, 512, 0, stream>>>(xbc, SgB, cumA, yb);
    k_diag<<<BATCHN * NCHUNK * 4, 256, 0, stream>>>(xbc, dtv, A_log, Dp, yb);
    k_norm<<<MPAD, 256, 0, stream>>>(yb, zx, norm_w, ynb);
    dim3 g2(DMODEL / 128, MPAD / 128);
    k_gemm128<<<g2, 256, 0, stream>>>(ynb, woutb, out, TOKENS, DMODEL, DINNER);
}

// Round 4
// 220.142 us; speedup vs baseline: 3.5120x; 1.4613x over previous
//
#include <hip/hip_runtime.h>
#include <hip/hip_bf16.h>

#define BATCHN 2
#define SEQL 1000
#define DMODEL 1024
#define DSTATE 128
#define HEADDIM 64
#define DINNER 2048
#define NHEADS 32
#define CONVDIM 2304   // DINNER + 2*DSTATE
#define NPROJ 4384     // 2*DINNER + 2*DSTATE + NHEADS
#define TOKENS 2000
#define MPAD 2048      // tokens padded to 128 multiple
#define NPAD1 4480     // NPROJ padded to 128 multiple
#define QC 64          // our chunk length
#define NCH 16         // chunks per sequence (16*64 = 1024 >= 1000)

typedef __bf16 bfx8 __attribute__((ext_vector_type(8)));
typedef float fx4 __attribute__((ext_vector_type(4)));
typedef unsigned short u16x8 __attribute__((ext_vector_type(8)));

__device__ __forceinline__ unsigned short f2bf(float f) {
    unsigned int u = __builtin_bit_cast(unsigned int, f);
    u += 0x7FFFu + ((u >> 16) & 1u);
    return (unsigned short)(u >> 16);
}
__device__ __forceinline__ float bf2f(unsigned short u) {
    return __builtin_bit_cast(float, ((unsigned int)u) << 16);
}

__device__ __forceinline__ void gload16(const void* g, void* l) {
    __builtin_amdgcn_global_load_lds(
        (const __attribute__((address_space(1))) void*)g,
        (__attribute__((address_space(3))) void*)l, 16, 0, 0);
}

// ---------------- fp32 -> bf16 conversion with zero padding ----------------
__global__ __launch_bounds__(256) void k_f2bf_pad(const float* __restrict__ src,
                                                  unsigned short* __restrict__ dst,
                                                  int n4src, int n4dst) {
    int i = blockIdx.x * 256 + threadIdx.x;
    if (i >= n4dst) return;
    ushort4 o = {0, 0, 0, 0};
    if (i < n4src) {
        float4 v = ((const float4*)src)[i];
        o.x = f2bf(v.x); o.y = f2bf(v.y); o.z = f2bf(v.z); o.w = f2bf(v.w);
    }
    ((ushort4*)dst)[i] = o;
}

// ---------------- dt head projection in fp32 (exp-sensitive path) ----------------
__global__ __launch_bounds__(256) void k_dt(const float* __restrict__ x,
                                            const float* __restrict__ win,
                                            const float* __restrict__ dt_bias,
                                            float* __restrict__ dtv) {
    __shared__ float sx[8][1024];
    int t = threadIdx.x;
    int tok0 = blockIdx.x * 8;
    for (int i = t; i < 8 * 256; i += 256) {
        int tok = i >> 8, k4 = i & 255;
        ((float4*)&sx[tok][0])[k4] = ((const float4*)(x + (size_t)(tok0 + tok) * DMODEL))[k4];
    }
    __syncthreads();
    int tl = t >> 5, h = t & 31;
    const float4* wr_ = (const float4*)(win + (size_t)(2 * DINNER + 2 * DSTATE + h) * DMODEL);
    const float4* xr = (const float4*)&sx[tl][0];
    float acc = 0.f;
    #pragma unroll 4
    for (int k = 0; k < 256; ++k) {
        float4 a = xr[k], b = wr_[k];
        acc += a.x * b.x + a.y * b.y + a.z * b.z + a.w * b.w;
    }
    float v = acc + dt_bias[h];
    dtv[(size_t)(tok0 + tl) * NHEADS + h] = fmaxf(v, 0.f) + log1pf(expf(-fabsf(v)));
}

// ---------------- bf16 NT GEMM (m97 structure): C[M][N] = A[M][K] * B[N][K]^T ----
__global__ __launch_bounds__(256) void k_gemm128(const unsigned short* __restrict__ A,
                                                 const unsigned short* __restrict__ B,
                                                 float* __restrict__ C,
                                                 int Mstore, int N, int K) {
    __shared__ __attribute__((aligned(16))) unsigned short As[4096];  // 128 x 32
    __shared__ __attribute__((aligned(16))) unsigned short Bs[4096];
    int t = threadIdx.x;
    int lane = t & 63, wave = t >> 6;
    int wr = wave >> 1, wc = wave & 1;
    int m0 = blockIdx.y * 128, n0 = blockIdx.x * 128;
    int fr = lane & 15, fk = (lane >> 4) * 8;
    fx4 acc[4][4] = {};
    const unsigned short* Ag = A + (size_t)(m0 + (t >> 2)) * K + (t & 3) * 8;
    const unsigned short* Bg = B + (size_t)(n0 + (t >> 2)) * K + (t & 3) * 8;
    for (int k0 = 0; k0 < K; k0 += 32) {
        __syncthreads();
        gload16(Ag + k0, As + t * 8);
        gload16(Ag + (size_t)64 * K + k0, As + 2048 + t * 8);
        gload16(Bg + k0, Bs + t * 8);
        gload16(Bg + (size_t)64 * K + k0, Bs + 2048 + t * 8);
        __syncthreads();
        bfx8 a[4], b[4];
        #pragma unroll
        for (int m = 0; m < 4; ++m) a[m] = *(const bfx8*)&As[(wr * 64 + m * 16 + fr) * 32 + fk];
        #pragma unroll
        for (int n = 0; n < 4; ++n) b[n] = *(const bfx8*)&Bs[(wc * 64 + n * 16 + fr) * 32 + fk];
        #pragma unroll
        for (int m = 0; m < 4; ++m)
            #pragma unroll
            for (int n = 0; n < 4; ++n)
                acc[m][n] = __builtin_amdgcn_mfma_f32_16x16x32_bf16(a[m], b[n], acc[m][n], 0, 0, 0);
    }
    #pragma unroll
    for (int m = 0; m < 4; ++m) {
        int rbase = m0 + wr * 64 + m * 16 + (lane >> 4) * 4;
        #pragma unroll
        for (int i = 0; i < 4; ++i) {
            int r = rbase + i;
            if (r < Mstore) {
                #pragma unroll
                for (int n = 0; n < 4; ++n) {
                    int c = n0 + wc * 64 + n * 16 + fr;
                    if (c < N) C[(size_t)r * N + c] = acc[m][n][i];
                }
            }
        }
    }
}

// ---------------- depthwise causal conv (width 4) + bias + SiLU ----------------
__global__ __launch_bounds__(256) void k_conv(const float* __restrict__ zx,
                                              const float* __restrict__ cw,
                                              const float* __restrict__ cb,
                                              float* __restrict__ xbc) {
    int idx = blockIdx.x * 256 + threadIdx.x;
    if (idx >= TOKENS * CONVDIM) return;
    int row = idx / CONVDIM;
    int col = idx - row * CONVDIM;
    int l = row % SEQL;
    float acc = cb[col];
    #pragma unroll
    for (int j = 0; j < 4; ++j) {
        int lj = l - 3 + j;
        if (lj >= 0)
            acc += zx[(size_t)(row - 3 + j) * NPROJ + DINNER + col] * cw[col * 4 + j];
    }
    xbc[idx] = acc / (1.f + expf(-acc));
}

// ================= SSD via MFMA, chunk = 64 =================
// k_tile: per (b,h,c): G = C B^T; W = G .* decay; Y_diag = W Xd^T ; Sc = Xd^T Bd^T
#define SCW 136
#define SWW 72
__global__ __launch_bounds__(256) void k_tile(const float* __restrict__ xbc,
                                              const float* __restrict__ dtv,
                                              const float* __restrict__ A_log,
                                              const float* __restrict__ Dp,
                                              float* __restrict__ ybuf,
                                              float* __restrict__ Sg,
                                              float* __restrict__ cumA) {
    __shared__ unsigned short sC[64 * SCW];
    __shared__ unsigned short sB[64 * SCW];   // reused as W [64*SWW] after G
    __shared__ unsigned short sBdT[128 * SWW];
    __shared__ unsigned short sXdT[64 * SWW];
    __shared__ unsigned short sXr[64 * SWW];
    __shared__ float sAcs[64];
    __shared__ float sdt[64];
    int bid = blockIdx.x;
    int b = bid / (NHEADS * NCH);
    int r = bid % (NHEADS * NCH);
    int h = r / NCH, c = r % NCH;
    int t = threadIdx.x;
    int lane = t & 63, wave = t >> 6;
    // dt + inclusive prefix of A*dt over the chunk (wave 0)
    if (t < 64) {
        int tok = c * QC + t;
        float d = (tok < SEQL) ? dtv[(size_t)(b * SEQL + tok) * NHEADS + h] : 0.f;
        float A = -expf(A_log[h]);
        float v = A * d;
        #pragma unroll
        for (int off = 1; off < 64; off <<= 1) {
            float u = __shfl_up(v, off, 64);
            if (lane >= off) v += u;
        }
        sdt[t] = d;
        sAcs[t] = v;
        cumA[(size_t)bid * 64 + t] = v;
    }
    __syncthreads();
    float Aend = sAcs[63];
    // stage C, B, BdT (bf16)
    for (int i = t; i < 64 * 32; i += 256) {
        int l = i >> 5, n4 = (i & 31) * 4;
        int tok = c * QC + l;
        float4 cv = {0, 0, 0, 0}, bv = {0, 0, 0, 0};
        if (tok < SEQL) {
            const float* base = xbc + (size_t)(b * SEQL + tok) * CONVDIM;
            bv = *(const float4*)(base + DINNER + n4);
            cv = *(const float4*)(base + DINNER + DSTATE + n4);
        }
        float dec = expf(Aend - sAcs[l]);
        sC[l * SCW + n4 + 0] = f2bf(cv.x); sC[l * SCW + n4 + 1] = f2bf(cv.y);
        sC[l * SCW + n4 + 2] = f2bf(cv.z); sC[l * SCW + n4 + 3] = f2bf(cv.w);
        sB[l * SCW + n4 + 0] = f2bf(bv.x); sB[l * SCW + n4 + 1] = f2bf(bv.y);
        sB[l * SCW + n4 + 2] = f2bf(bv.z); sB[l * SCW + n4 + 3] = f2bf(bv.w);
        sBdT[(n4 + 0) * SWW + l] = f2bf(bv.x * dec);
        sBdT[(n4 + 1) * SWW + l] = f2bf(bv.y * dec);
        sBdT[(n4 + 2) * SWW + l] = f2bf(bv.z * dec);
        sBdT[(n4 + 3) * SWW + l] = f2bf(bv.w * dec);
    }
    // stage X (raw, and dt-scaled transposed)
    for (int i = t; i < 64 * 16; i += 256) {
        int l = i >> 4, p4 = (i & 15) * 4;
        int tok = c * QC + l;
        float4 xv = {0, 0, 0, 0};
        if (tok < SEQL) xv = *(const float4*)(xbc + (size_t)(b * SEQL + tok) * CONVDIM + h * 64 + p4);
        float d = sdt[l];
        sXr[l * SWW + p4 + 0] = f2bf(xv.x); sXr[l * SWW + p4 + 1] = f2bf(xv.y);
        sXr[l * SWW + p4 + 2] = f2bf(xv.z); sXr[l * SWW + p4 + 3] = f2bf(xv.w);
        sXdT[(p4 + 0) * SWW + l] = f2bf(xv.x * d);
        sXdT[(p4 + 1) * SWW + l] = f2bf(xv.y * d);
        sXdT[(p4 + 2) * SWW + l] = f2bf(xv.z * d);
        sXdT[(p4 + 3) * SWW + l] = f2bf(xv.w * d);
    }
    __syncthreads();
    int fr = lane & 15, fk8 = (lane >> 4) * 8;
    int wr = wave >> 1, wc = wave & 1;
    // G = C * B^T  (64x64, K=128)
    fx4 g[2][2] = {};
    #pragma unroll
    for (int k = 0; k < 4; ++k) {
        bfx8 a0 = *(const bfx8*)&sC[(wr * 32 + fr) * SCW + k * 32 + fk8];
        bfx8 a1 = *(const bfx8*)&sC[(wr * 32 + 16 + fr) * SCW + k * 32 + fk8];
        bfx8 b0 = *(const bfx8*)&sB[(wc * 32 + fr) * SCW + k * 32 + fk8];
        bfx8 b1 = *(const bfx8*)&sB[(wc * 32 + 16 + fr) * SCW + k * 32 + fk8];
        g[0][0] = __builtin_amdgcn_mfma_f32_16x16x32_bf16(a0, b0, g[0][0], 0, 0, 0);
        g[0][1] = __builtin_amdgcn_mfma_f32_16x16x32_bf16(a0, b1, g[0][1], 0, 0, 0);
        g[1][0] = __builtin_amdgcn_mfma_f32_16x16x32_bf16(a1, b0, g[1][0], 0, 0, 0);
        g[1][1] = __builtin_amdgcn_mfma_f32_16x16x32_bf16(a1, b1, g[1][1], 0, 0, 0);
    }
    __syncthreads();   // all reads of sB done before overwrite with W
    // W = tril(G) .* exp(Acs[l]-Acs[s])   (dt folded into Xd already)
    int rb = wr * 32 + (lane >> 4) * 4;
    int cb = wc * 32 + fr;
    #pragma unroll
    for (int m = 0; m < 2; ++m)
        #pragma unroll
        for (int n = 0; n < 2; ++n)
            #pragma unroll
            for (int i = 0; i < 4; ++i) {
                int row = rb + m * 16 + i, col = cb + n * 16;
                float wv = (col <= row) ? g[m][n][i] * expf(sAcs[row] - sAcs[col]) : 0.f;
                sB[row * SWW + col] = f2bf(wv);
            }
    __syncthreads();
    // Y_diag = W * Xd^T (64x64, K=64)   and   Sc = Xd^T * Bd^T (64x128, K=64)
    fx4 yd[2][2] = {};
    fx4 sc[2][4] = {};
    #pragma unroll
    for (int k = 0; k < 2; ++k) {
        bfx8 aW0 = *(const bfx8*)&sB[(wr * 32 + fr) * SWW + k * 32 + fk8];
        bfx8 aW1 = *(const bfx8*)&sB[(wr * 32 + 16 + fr) * SWW + k * 32 + fk8];
        bfx8 bX0 = *(const bfx8*)&sXdT[(wc * 32 + fr) * SWW + k * 32 + fk8];
        bfx8 bX1 = *(const bfx8*)&sXdT[(wc * 32 + 16 + fr) * SWW + k * 32 + fk8];
        yd[0][0] = __builtin_amdgcn_mfma_f32_16x16x32_bf16(aW0, bX0, yd[0][0], 0, 0, 0);
        yd[0][1] = __builtin_amdgcn_mfma_f32_16x16x32_bf16(aW0, bX1, yd[0][1], 0, 0, 0);
        yd[1][0] = __builtin_amdgcn_mfma_f32_16x16x32_bf16(aW1, bX0, yd[1][0], 0, 0, 0);
        yd[1][1] = __builtin_amdgcn_mfma_f32_16x16x32_bf16(aW1, bX1, yd[1][1], 0, 0, 0);
        bfx8 aX0 = *(const bfx8*)&sXdT[(wr * 32 + fr) * SWW + k * 32 + fk8];
        bfx8 aX1 = *(const bfx8*)&sXdT[(wr * 32 + 16 + fr) * SWW + k * 32 + fk8];
        #pragma unroll
        for (int j = 0; j < 4; ++j) {
            bfx8 bB = *(const bfx8*)&sBdT[(wc * 64 + j * 16 + fr) * SWW + k * 32 + fk8];
            sc[0][j] = __builtin_amdgcn_mfma_f32_16x16x32_bf16(aX0, bB, sc[0][j], 0, 0, 0);
            sc[1][j] = __builtin_amdgcn_mfma_f32_16x16x32_bf16(aX1, bB, sc[1][j], 0, 0, 0);
        }
    }
    // epilogue: Y_diag + D*x -> ybuf ; Sc -> Sg
    float Dh = Dp[h];
    #pragma unroll
    for (int m = 0; m < 2; ++m)
        #pragma unroll
        for (int i = 0; i < 4; ++i) {
            int row = rb + m * 16 + i;      // l
            int tok = c * QC + row;
            if (tok < SEQL) {
                #pragma unroll
                for (int n = 0; n < 2; ++n) {
                    int col = cb + n * 16;  // p
                    float xr = bf2f(sXr[row * SWW + col]);
                    ybuf[(size_t)(b * SEQL + tok) * DINNER + h * 64 + col] = yd[m][n][i] + Dh * xr;
                }
            }
        }
    #pragma unroll
    for (int m = 0; m < 2; ++m)
        #pragma unroll
        for (int i = 0; i < 4; ++i) {
            int p = rb + m * 16 + i;
            #pragma unroll
            for (int j = 0; j < 4; ++j) {
                int n = wc * 64 + j * 16 + fr;
                Sg[(size_t)bid * 8192 + p * 128 + n] = sc[m][j][i];
            }
        }
}

// k_scan2v: inter-chunk recurrence over NCH chunks; Sg in-place -> incoming states
__global__ __launch_bounds__(256) void k_scan2v(float* __restrict__ Sg,
                                                const float* __restrict__ cumA) {
    int bid = blockIdx.x;          // 64 bh * 32 sub
    int bh = bid >> 5, sub = bid & 31;
    int e = sub * 256 + threadIdx.x;
    __shared__ float sT[NCH];
    if (threadIdx.x < NCH)
        sT[threadIdx.x] = cumA[((size_t)(bh * NCH) + threadIdx.x) * 64 + 63];
    __syncthreads();
    float S = 0.f;
    size_t base = (size_t)bh * NCH * 8192 + e;
    for (int g = 0; g < NCH; ++g) {
        size_t off = base + (size_t)g * 8192;
        float sg = Sg[off];
        Sg[off] = S;
        S = expf(sT[g]) * S + sg;
    }
}

// k_yoff: Y += exp(Acs[l]) * (C * S_in^T)   per (b,h,c), c>=1
__global__ __launch_bounds__(256) void k_yoff(const float* __restrict__ xbc,
                                              const float* __restrict__ Sg,
                                              const float* __restrict__ cumA,
                                              float* __restrict__ ybuf) {
    int bid = blockIdx.x;
    int b = bid / (NHEADS * NCH);
    int r = bid % (NHEADS * NCH);
    int h = r / NCH, c = r % NCH;
    if (c == 0) return;
    __shared__ unsigned short sC[64 * SCW];
    __shared__ unsigned short sS[64 * SCW];
    __shared__ float sE[64];
    int t = threadIdx.x;
    int lane = t & 63, wave = t >> 6;
    if (t < 64) sE[t] = expf(cumA[(size_t)bid * 64 + t]);
    for (int i = t; i < 64 * 32; i += 256) {
        int l = i >> 5, n4 = (i & 31) * 4;
        int tok = c * QC + l;
        float4 cv = {0, 0, 0, 0};
        if (tok < SEQL)
            cv = *(const float4*)(xbc + (size_t)(b * SEQL + tok) * CONVDIM + DINNER + DSTATE + n4);
        sC[l * SCW + n4 + 0] = f2bf(cv.x); sC[l * SCW + n4 + 1] = f2bf(cv.y);
        sC[l * SCW + n4 + 2] = f2bf(cv.z); sC[l * SCW + n4 + 3] = f2bf(cv.w);
        float4 sv = *(const float4*)(Sg + (size_t)bid * 8192 + l * 128 + n4);  // rows = p
        sS[l * SCW + n4 + 0] = f2bf(sv.x); sS[l * SCW + n4 + 1] = f2bf(sv.y);
        sS[l * SCW + n4 + 2] = f2bf(sv.z); sS[l * SCW + n4 + 3] = f2bf(sv.w);
    }
    __syncthreads();
    int fr = lane & 15, fk8 = (lane >> 4) * 8;
    int wr = wave >> 1, wc = wave & 1;
    fx4 yo[2][2] = {};
    #pragma unroll
    for (int k = 0; k < 4; ++k) {
        bfx8 a0 = *(const bfx8*)&sC[(wr * 32 + fr) * SCW + k * 32 + fk8];
        bfx8 a1 = *(const bfx8*)&sC[(wr * 32 + 16 + fr) * SCW + k * 32 + fk8];
        bfx8 b0 = *(const bfx8*)&sS[(wc * 32 + fr) * SCW + k * 32 + fk8];
        bfx8 b1 = *(const bfx8*)&sS[(wc * 32 + 16 + fr) * SCW + k * 32 + fk8];
        yo[0][0] = __builtin_amdgcn_mfma_f32_16x16x32_bf16(a0, b0, yo[0][0], 0, 0, 0);
        yo[0][1] = __builtin_amdgcn_mfma_f32_16x16x32_bf16(a0, b1, yo[0][1], 0, 0, 0);
        yo[1][0] = __builtin_amdgcn_mfma_f32_16x16x32_bf16(a1, b0, yo[1][0], 0, 0, 0);
        yo[1][1] = __builtin_amdgcn_mfma_f32_16x16x32_bf16(a1, b1, yo[1][1], 0, 0, 0);
    }
    int rb = wr * 32 + (lane >> 4) * 4;
    int cb = wc * 32 + fr;
    #pragma unroll
    for (int m = 0; m < 2; ++m)
        #pragma unroll
        for (int i = 0; i < 4; ++i) {
            int row = rb + m * 16 + i;
            int tok = c * QC + row;
            if (tok < SEQL) {
                float e = sE[row];
                #pragma unroll
                for (int n = 0; n < 2; ++n) {
                    int col = cb + n * 16;
                    size_t off = (size_t)(b * SEQL + tok) * DINNER + h * 64 + col;
                    ybuf[off] += yo[m][n][i] * e;
                }
            }
        }
}

// ---------------- gate (y * silu(z)) + RMSNorm + norm_w, output bf16 (padded) ----
__global__ __launch_bounds__(256) void k_norm(const float* __restrict__ ybuf,
                                              const float* __restrict__ zx,
                                              const float* __restrict__ normw,
                                              unsigned short* __restrict__ ynb) {
    int row = blockIdx.x;
    int t = threadIdx.x;
    if (row >= TOKENS) {
        #pragma unroll
        for (int j = 0; j < 8; ++j) ynb[(size_t)row * DINNER + t + j * 256] = 0;
        return;
    }
    float v[8];
    float ss = 0.f;
    #pragma unroll
    for (int j = 0; j < 8; ++j) {
        int col = t + j * 256;
        float y = ybuf[(size_t)row * DINNER + col];
        float z = zx[(size_t)row * NPROJ + col];
        y *= z / (1.f + expf(-z));
        v[j] = y;
        ss += y * y;
    }
    #pragma unroll
    for (int off = 32; off > 0; off >>= 1) ss += __shfl_down(ss, off, 64);
    __shared__ float red[4];
    int lane = t & 63, wv = t >> 6;
    if (lane == 0) red[wv] = ss;
    __syncthreads();
    float tot = red[0] + red[1] + red[2] + red[3];
    float r = rsqrtf(tot * (1.f / DINNER) + 1e-5f);
    #pragma unroll
    for (int j = 0; j < 8; ++j) {
        int col = t + j * 256;
        ynb[(size_t)row * DINNER + col] = f2bf(v[j] * r * normw[col]);
    }
}

extern "C" void kernel_launch(void* const* d_in, const int* in_sizes, int n_in,
                              void* d_out, int out_size, void* d_ws, size_t ws_size,
                              hipStream_t stream) {
    const float* x       = (const float*)d_in[0];
    const float* W_in    = (const float*)d_in[1];
    const float* conv_w  = (const float*)d_in[2];
    const float* conv_b  = (const float*)d_in[3];
    const float* dt_bias = (const float*)d_in[4];
    const float* A_log   = (const float*)d_in[5];
    const float* Dp      = (const float*)d_in[6];
    const float* norm_w  = (const float*)d_in[7];
    const float* W_out   = (const float*)d_in[8];
    float* out = (float*)d_out;

    char* w = (char*)d_ws;
    auto alloc = [&](size_t bytes) {
        char* p = w;
        w += (bytes + 255) & ~(size_t)255;
        return p;
    };
    unsigned short* xb    = (unsigned short*)alloc((size_t)MPAD * DMODEL * 2);
    unsigned short* winb  = (unsigned short*)alloc((size_t)NPAD1 * DMODEL * 2);
    unsigned short* woutb = (unsigned short*)alloc((size_t)DMODEL * DINNER * 2);
    float* zx   = (float*)alloc((size_t)TOKENS * NPROJ * 4);
    float* xbc  = (float*)alloc((size_t)TOKENS * CONVDIM * 4);
    float* dtv  = (float*)alloc((size_t)TOKENS * NHEADS * 4);
    float* yb   = (float*)alloc((size_t)TOKENS * DINNER * 4);
    unsigned short* ynb = (unsigned short*)alloc((size_t)MPAD * DINNER * 2);
    float* Sg   = (float*)alloc((size_t)BATCHN * NHEADS * NCH * HEADDIM * DSTATE * 4);
    float* cumA = (float*)alloc((size_t)BATCHN * NHEADS * NCH * 64 * 4);

    int n4;
    n4 = MPAD * DMODEL / 4;
    k_f2bf_pad<<<(n4 + 255) / 256, 256, 0, stream>>>(x, xb, TOKENS * DMODEL / 4, n4);
    n4 = NPAD1 * DMODEL / 4;
    k_f2bf_pad<<<(n4 + 255) / 256, 256, 0, stream>>>(W_in, winb, NPROJ * DMODEL / 4, n4);
    n4 = DMODEL * DINNER / 4;
    k_f2bf_pad<<<(n4 + 255) / 256, 256, 0, stream>>>(W_out, woutb, n4, n4);
    k_dt<<<TOKENS / 8, 256, 0, stream>>>(x, W_in, dt_bias, dtv);
    dim3 g1(NPAD1 / 128, MPAD / 128);
    k_gemm128<<<g1, 256, 0, stream>>>(xb, winb, zx, TOKENS, NPROJ, DMODEL);
    k_conv<<<(TOKENS * CONVDIM + 255) / 256, 256, 0, stream>>>(zx, conv_w, conv_b, xbc);
    k_tile<<<BATCHN * NHEADS * NCH, 256, 0, stream>>>(xbc, dtv, A_log, Dp, yb, Sg, cumA);
    k_scan2v<<<BATCHN * NHEADS * 32, 256, 0, stream>>>(Sg, cumA);
    k_yoff<<<BATCHN * NHEADS * NCH, 256, 0, stream>>>(xbc, Sg, cumA, yb);
    k_norm<<<MPAD, 256, 0, stream>>>(yb, zx, norm_w, ynb);
    dim3 g2(DMODEL / 128, MPAD / 128);
    k_gemm128<<<g2, 256, 0, stream>>>(ynb, woutb, out, TOKENS, DMODEL, DINNER);
}

// Round 5
// 194.889 us; speedup vs baseline: 3.9671x; 1.1296x over previous
//
#include <hip/hip_runtime.h>
#include <hip/hip_bf16.h>

#define BATCHN 2
#define SEQL 1000
#define DMODEL 1024
#define DSTATE 128
#define HEADDIM 64
#define DINNER 2048
#define NHEADS 32
#define CONVDIM 2304   // DINNER + 2*DSTATE
#define NPROJ 4384     // 2*DINNER + 2*DSTATE + NHEADS
#define TOKENS 2000
#define MPAD 2048      // tokens padded to 128 multiple
#define NPAD1 4608     // NPROJ padded to 256 multiple
#define QC 64          // our chunk length
#define NCH 16         // chunks per sequence (16*64 = 1024 >= 1000)

typedef __bf16 bfx8 __attribute__((ext_vector_type(8)));
typedef float fx4 __attribute__((ext_vector_type(4)));
typedef unsigned short u16x8 __attribute__((ext_vector_type(8)));

__device__ __forceinline__ unsigned short f2bf(float f) {
    unsigned int u = __builtin_bit_cast(unsigned int, f);
    u += 0x7FFFu + ((u >> 16) & 1u);
    return (unsigned short)(u >> 16);
}
__device__ __forceinline__ float bf2f(unsigned short u) {
    return __builtin_bit_cast(float, ((unsigned int)u) << 16);
}

__device__ __forceinline__ void gload16(const void* g, void* l) {
    __builtin_amdgcn_global_load_lds(
        (const __attribute__((address_space(1))) void*)g,
        (__attribute__((address_space(3))) void*)l, 16, 0, 0);
}

// ---------------- fp32 -> bf16 conversion with zero padding ----------------
__global__ __launch_bounds__(256) void k_f2bf_pad(const float* __restrict__ src,
                                                  unsigned short* __restrict__ dst,
                                                  int n4src, int n4dst) {
    int i = blockIdx.x * 256 + threadIdx.x;
    if (i >= n4dst) return;
    ushort4 o = {0, 0, 0, 0};
    if (i < n4src) {
        float4 v = ((const float4*)src)[i];
        o.x = f2bf(v.x); o.y = f2bf(v.y); o.z = f2bf(v.z); o.w = f2bf(v.w);
    }
    ((ushort4*)dst)[i] = o;
}

// ---------------- dt head projection in fp32 (exp-sensitive path) ----------------
__global__ __launch_bounds__(256) void k_dt(const float* __restrict__ x,
                                            const float* __restrict__ win,
                                            const float* __restrict__ dt_bias,
                                            float* __restrict__ dtv) {
    __shared__ float sx[8][1024];
    int t = threadIdx.x;
    int tok0 = blockIdx.x * 8;
    for (int i = t; i < 8 * 256; i += 256) {
        int tok = i >> 8, k4 = i & 255;
        ((float4*)&sx[tok][0])[k4] = ((const float4*)(x + (size_t)(tok0 + tok) * DMODEL))[k4];
    }
    __syncthreads();
    int tl = t >> 5, h = t & 31;
    const float4* wr_ = (const float4*)(win + (size_t)(2 * DINNER + 2 * DSTATE + h) * DMODEL);
    const float4* xr = (const float4*)&sx[tl][0];
    float acc = 0.f;
    #pragma unroll 4
    for (int k = 0; k < 256; ++k) {
        float4 a = xr[k], b = wr_[k];
        acc += a.x * b.x + a.y * b.y + a.z * b.z + a.w * b.w;
    }
    float v = acc + dt_bias[h];
    dtv[(size_t)(tok0 + tl) * NHEADS + h] = fmaxf(v, 0.f) + log1pf(expf(-fabsf(v)));
}

// ---------------- bf16 NT GEMM: 128x256 tile, 512 thr, dbuf 2-phase ----------
// C[M][N] = A[M][K] * B[N][K]^T over K-chunk [z*kc, (z+1)*kc); C += z*pstride.
// LDS source-swizzled (slot ^= row&3) to cut ds_read bank conflicts 8->4 way.
__global__ __launch_bounds__(512) void k_gemm256(const unsigned short* __restrict__ A,
                                                 const unsigned short* __restrict__ B,
                                                 float* __restrict__ C,
                                                 int Mstore, int N, int K,
                                                 int kc, size_t pstride) {
    __shared__ __attribute__((aligned(16))) unsigned short As[2][4096];   // 128 x 32
    __shared__ __attribute__((aligned(16))) unsigned short Bs[2][8192];   // 256 x 32
    int t = threadIdx.x;
    int lane = t & 63, wave = t >> 6;
    int wr = wave >> 2, wc = wave & 3;
    int m0 = blockIdx.y * 128, n0 = blockIdx.x * 256;
    int k0 = blockIdx.z * kc;
    // staging: thread t -> row t>>2, physical slot t&3; source col swizzled
    int swcol8 = (((t & 3) ^ ((t >> 2) & 3)) * 8);
    const unsigned short* Ag  = A + (size_t)(m0 + (t >> 2)) * K + k0 + swcol8;
    const unsigned short* Bg0 = B + (size_t)(n0 + (t >> 2)) * K + k0 + swcol8;
    const unsigned short* Bg1 = Bg0 + (size_t)128 * K;
    gload16(Ag, &As[0][t * 8]);
    gload16(Bg0, &Bs[0][t * 8]);
    gload16(Bg1, &Bs[0][4096 + t * 8]);
    fx4 acc[4][4] = {};
    int fr = lane & 15, ks = lane >> 4;
    __syncthreads();
    int cur = 0;
    for (int kk = 32; kk < kc; kk += 32) {
        gload16(Ag + kk, &As[cur ^ 1][t * 8]);
        gload16(Bg0 + kk, &Bs[cur ^ 1][t * 8]);
        gload16(Bg1 + kk, &Bs[cur ^ 1][4096 + t * 8]);
        bfx8 a[4], b[4];
        #pragma unroll
        for (int m = 0; m < 4; ++m) {
            int R = wr * 64 + m * 16 + fr;
            a[m] = *(const bfx8*)&As[cur][R * 32 + ((ks ^ (R & 3)) << 3)];
        }
        #pragma unroll
        for (int n = 0; n < 4; ++n) {
            int R = wc * 64 + n * 16 + fr;
            b[n] = *(const bfx8*)&Bs[cur][R * 32 + ((ks ^ (R & 3)) << 3)];
        }
        #pragma unroll
        for (int m = 0; m < 4; ++m)
            #pragma unroll
            for (int n = 0; n < 4; ++n)
                acc[m][n] = __builtin_amdgcn_mfma_f32_16x16x32_bf16(a[m], b[n], acc[m][n], 0, 0, 0);
        __syncthreads();
        cur ^= 1;
    }
    {   // last K-step (no stage)
        bfx8 a[4], b[4];
        #pragma unroll
        for (int m = 0; m < 4; ++m) {
            int R = wr * 64 + m * 16 + fr;
            a[m] = *(const bfx8*)&As[cur][R * 32 + ((ks ^ (R & 3)) << 3)];
        }
        #pragma unroll
        for (int n = 0; n < 4; ++n) {
            int R = wc * 64 + n * 16 + fr;
            b[n] = *(const bfx8*)&Bs[cur][R * 32 + ((ks ^ (R & 3)) << 3)];
        }
        #pragma unroll
        for (int m = 0; m < 4; ++m)
            #pragma unroll
            for (int n = 0; n < 4; ++n)
                acc[m][n] = __builtin_amdgcn_mfma_f32_16x16x32_bf16(a[m], b[n], acc[m][n], 0, 0, 0);
    }
    float* Cz = C + (size_t)blockIdx.z * pstride;
    #pragma unroll
    for (int m = 0; m < 4; ++m) {
        int rbase = m0 + wr * 64 + m * 16 + (lane >> 4) * 4;
        #pragma unroll
        for (int i = 0; i < 4; ++i) {
            int r = rbase + i;
            if (r < Mstore) {
                #pragma unroll
                for (int n = 0; n < 4; ++n) {
                    int c = n0 + wc * 64 + n * 16 + fr;
                    if (c < N) Cz[(size_t)r * N + c] = acc[m][n][i];
                }
            }
        }
    }
}

// ---------------- split-K reduce: out = sum_z part[z] ----------------
__global__ __launch_bounds__(256) void k_red(const float* __restrict__ part,
                                             float* __restrict__ out, int n4, size_t pstride4) {
    int i = blockIdx.x * 256 + threadIdx.x;
    if (i >= n4) return;
    const float4* p = (const float4*)part;
    float4 v0 = p[i];
    float4 v1 = p[i + pstride4];
    float4 v2 = p[i + 2 * pstride4];
    float4 v3 = p[i + 3 * pstride4];
    float4 o;
    o.x = (v0.x + v1.x) + (v2.x + v3.x);
    o.y = (v0.y + v1.y) + (v2.y + v3.y);
    o.z = (v0.z + v1.z) + (v2.z + v3.z);
    o.w = (v0.w + v1.w) + (v2.w + v3.w);
    ((float4*)out)[i] = o;
}

// ---------------- depthwise causal conv (width 4) + bias + SiLU ----------------
__global__ __launch_bounds__(256) void k_conv(const float* __restrict__ zx,
                                              const float* __restrict__ cw,
                                              const float* __restrict__ cb,
                                              float* __restrict__ xbc) {
    int idx = blockIdx.x * 256 + threadIdx.x;
    if (idx >= TOKENS * CONVDIM) return;
    int row = idx / CONVDIM;
    int col = idx - row * CONVDIM;
    int l = row % SEQL;
    float acc = cb[col];
    #pragma unroll
    for (int j = 0; j < 4; ++j) {
        int lj = l - 3 + j;
        if (lj >= 0)
            acc += zx[(size_t)(row - 3 + j) * NPROJ + DINNER + col] * cw[col * 4 + j];
    }
    xbc[idx] = acc / (1.f + expf(-acc));
}

// ================= SSD via MFMA, chunk = 64 =================
#define SCW 136
#define SWW 72
__global__ __launch_bounds__(256) void k_tile(const float* __restrict__ xbc,
                                              const float* __restrict__ dtv,
                                              const float* __restrict__ A_log,
                                              const float* __restrict__ Dp,
                                              float* __restrict__ ybuf,
                                              float* __restrict__ Sg,
                                              float* __restrict__ cumA) {
    __shared__ unsigned short sC[64 * SCW];
    __shared__ unsigned short sB[64 * SCW];   // reused as W [64*SWW] after G
    __shared__ unsigned short sBdT[128 * SWW];
    __shared__ unsigned short sXdT[64 * SWW];
    __shared__ unsigned short sXr[64 * SWW];
    __shared__ float sAcs[64];
    __shared__ float sdt[64];
    int bid = blockIdx.x;
    int b = bid / (NHEADS * NCH);
    int r = bid % (NHEADS * NCH);
    int h = r / NCH, c = r % NCH;
    int t = threadIdx.x;
    int lane = t & 63, wave = t >> 6;
    if (t < 64) {
        int tok = c * QC + t;
        float d = (tok < SEQL) ? dtv[(size_t)(b * SEQL + tok) * NHEADS + h] : 0.f;
        float A = -expf(A_log[h]);
        float v = A * d;
        #pragma unroll
        for (int off = 1; off < 64; off <<= 1) {
            float u = __shfl_up(v, off, 64);
            if (lane >= off) v += u;
        }
        sdt[t] = d;
        sAcs[t] = v;
        cumA[(size_t)bid * 64 + t] = v;
    }
    __syncthreads();
    float Aend = sAcs[63];
    for (int i = t; i < 64 * 32; i += 256) {
        int l = i >> 5, n4 = (i & 31) * 4;
        int tok = c * QC + l;
        float4 cv = {0, 0, 0, 0}, bv = {0, 0, 0, 0};
        if (tok < SEQL) {
            const float* base = xbc + (size_t)(b * SEQL + tok) * CONVDIM;
            bv = *(const float4*)(base + DINNER + n4);
            cv = *(const float4*)(base + DINNER + DSTATE + n4);
        }
        float dec = expf(Aend - sAcs[l]);
        sC[l * SCW + n4 + 0] = f2bf(cv.x); sC[l * SCW + n4 + 1] = f2bf(cv.y);
        sC[l * SCW + n4 + 2] = f2bf(cv.z); sC[l * SCW + n4 + 3] = f2bf(cv.w);
        sB[l * SCW + n4 + 0] = f2bf(bv.x); sB[l * SCW + n4 + 1] = f2bf(bv.y);
        sB[l * SCW + n4 + 2] = f2bf(bv.z); sB[l * SCW + n4 + 3] = f2bf(bv.w);
        sBdT[(n4 + 0) * SWW + l] = f2bf(bv.x * dec);
        sBdT[(n4 + 1) * SWW + l] = f2bf(bv.y * dec);
        sBdT[(n4 + 2) * SWW + l] = f2bf(bv.z * dec);
        sBdT[(n4 + 3) * SWW + l] = f2bf(bv.w * dec);
    }
    for (int i = t; i < 64 * 16; i += 256) {
        int l = i >> 4, p4 = (i & 15) * 4;
        int tok = c * QC + l;
        float4 xv = {0, 0, 0, 0};
        if (tok < SEQL) xv = *(const float4*)(xbc + (size_t)(b * SEQL + tok) * CONVDIM + h * 64 + p4);
        float d = sdt[l];
        sXr[l * SWW + p4 + 0] = f2bf(xv.x); sXr[l * SWW + p4 + 1] = f2bf(xv.y);
        sXr[l * SWW + p4 + 2] = f2bf(xv.z); sXr[l * SWW + p4 + 3] = f2bf(xv.w);
        sXdT[(p4 + 0) * SWW + l] = f2bf(xv.x * d);
        sXdT[(p4 + 1) * SWW + l] = f2bf(xv.y * d);
        sXdT[(p4 + 2) * SWW + l] = f2bf(xv.z * d);
        sXdT[(p4 + 3) * SWW + l] = f2bf(xv.w * d);
    }
    __syncthreads();
    int fr = lane & 15, fk8 = (lane >> 4) * 8;
    int wr = wave >> 1, wc = wave & 1;
    fx4 g[2][2] = {};
    #pragma unroll
    for (int k = 0; k < 4; ++k) {
        bfx8 a0 = *(const bfx8*)&sC[(wr * 32 + fr) * SCW + k * 32 + fk8];
        bfx8 a1 = *(const bfx8*)&sC[(wr * 32 + 16 + fr) * SCW + k * 32 + fk8];
        bfx8 b0 = *(const bfx8*)&sB[(wc * 32 + fr) * SCW + k * 32 + fk8];
        bfx8 b1 = *(const bfx8*)&sB[(wc * 32 + 16 + fr) * SCW + k * 32 + fk8];
        g[0][0] = __builtin_amdgcn_mfma_f32_16x16x32_bf16(a0, b0, g[0][0], 0, 0, 0);
        g[0][1] = __builtin_amdgcn_mfma_f32_16x16x32_bf16(a0, b1, g[0][1], 0, 0, 0);
        g[1][0] = __builtin_amdgcn_mfma_f32_16x16x32_bf16(a1, b0, g[1][0], 0, 0, 0);
        g[1][1] = __builtin_amdgcn_mfma_f32_16x16x32_bf16(a1, b1, g[1][1], 0, 0, 0);
    }
    __syncthreads();
    int rb = wr * 32 + (lane >> 4) * 4;
    int cb = wc * 32 + fr;
    #pragma unroll
    for (int m = 0; m < 2; ++m)
        #pragma unroll
        for (int n = 0; n < 2; ++n)
            #pragma unroll
            for (int i = 0; i < 4; ++i) {
                int row = rb + m * 16 + i, col = cb + n * 16;
                float wv = (col <= row) ? g[m][n][i] * expf(sAcs[row] - sAcs[col]) : 0.f;
                sB[row * SWW + col] = f2bf(wv);
            }
    __syncthreads();
    fx4 yd[2][2] = {};
    fx4 sc[2][4] = {};
    #pragma unroll
    for (int k = 0; k < 2; ++k) {
        bfx8 aW0 = *(const bfx8*)&sB[(wr * 32 + fr) * SWW + k * 32 + fk8];
        bfx8 aW1 = *(const bfx8*)&sB[(wr * 32 + 16 + fr) * SWW + k * 32 + fk8];
        bfx8 bX0 = *(const bfx8*)&sXdT[(wc * 32 + fr) * SWW + k * 32 + fk8];
        bfx8 bX1 = *(const bfx8*)&sXdT[(wc * 32 + 16 + fr) * SWW + k * 32 + fk8];
        yd[0][0] = __builtin_amdgcn_mfma_f32_16x16x32_bf16(aW0, bX0, yd[0][0], 0, 0, 0);
        yd[0][1] = __builtin_amdgcn_mfma_f32_16x16x32_bf16(aW0, bX1, yd[0][1], 0, 0, 0);
        yd[1][0] = __builtin_amdgcn_mfma_f32_16x16x32_bf16(aW1, bX0, yd[1][0], 0, 0, 0);
        yd[1][1] = __builtin_amdgcn_mfma_f32_16x16x32_bf16(aW1, bX1, yd[1][1], 0, 0, 0);
        bfx8 aX0 = *(const bfx8*)&sXdT[(wr * 32 + fr) * SWW + k * 32 + fk8];
        bfx8 aX1 = *(const bfx8*)&sXdT[(wr * 32 + 16 + fr) * SWW + k * 32 + fk8];
        #pragma unroll
        for (int j = 0; j < 4; ++j) {
            bfx8 bB = *(const bfx8*)&sBdT[(wc * 64 + j * 16 + fr) * SWW + k * 32 + fk8];
            sc[0][j] = __builtin_amdgcn_mfma_f32_16x16x32_bf16(aX0, bB, sc[0][j], 0, 0, 0);
            sc[1][j] = __builtin_amdgcn_mfma_f32_16x16x32_bf16(aX1, bB, sc[1][j], 0, 0, 0);
        }
    }
    float Dh = Dp[h];
    #pragma unroll
    for (int m = 0; m < 2; ++m)
        #pragma unroll
        for (int i = 0; i < 4; ++i) {
            int row = rb + m * 16 + i;
            int tok = c * QC + row;
            if (tok < SEQL) {
                #pragma unroll
                for (int n = 0; n < 2; ++n) {
                    int col = cb + n * 16;
                    float xr = bf2f(sXr[row * SWW + col]);
                    ybuf[(size_t)(b * SEQL + tok) * DINNER + h * 64 + col] = yd[m][n][i] + Dh * xr;
                }
            }
        }
    #pragma unroll
    for (int m = 0; m < 2; ++m)
        #pragma unroll
        for (int i = 0; i < 4; ++i) {
            int p = rb + m * 16 + i;
            #pragma unroll
            for (int j = 0; j < 4; ++j) {
                int n = wc * 64 + j * 16 + fr;
                Sg[(size_t)bid * 8192 + p * 128 + n] = sc[m][j][i];
            }
        }
}

__global__ __launch_bounds__(256) void k_scan2v(float* __restrict__ Sg,
                                                const float* __restrict__ cumA) {
    int bid = blockIdx.x;
    int bh = bid >> 5, sub = bid & 31;
    int e = sub * 256 + threadIdx.x;
    __shared__ float sT[NCH];
    if (threadIdx.x < NCH)
        sT[threadIdx.x] = cumA[((size_t)(bh * NCH) + threadIdx.x) * 64 + 63];
    __syncthreads();
    float S = 0.f;
    size_t base = (size_t)bh * NCH * 8192 + e;
    for (int g = 0; g < NCH; ++g) {
        size_t off = base + (size_t)g * 8192;
        float sg = Sg[off];
        Sg[off] = S;
        S = expf(sT[g]) * S + sg;
    }
}

__global__ __launch_bounds__(256) void k_yoff(const float* __restrict__ xbc,
                                              const float* __restrict__ Sg,
                                              const float* __restrict__ cumA,
                                              float* __restrict__ ybuf) {
    int bid = blockIdx.x;
    int b = bid / (NHEADS * NCH);
    int r = bid % (NHEADS * NCH);
    int h = r / NCH, c = r % NCH;
    if (c == 0) return;
    __shared__ unsigned short sC[64 * SCW];
    __shared__ unsigned short sS[64 * SCW];
    __shared__ float sE[64];
    int t = threadIdx.x;
    int lane = t & 63, wave = t >> 6;
    if (t < 64) sE[t] = expf(cumA[(size_t)bid * 64 + t]);
    for (int i = t; i < 64 * 32; i += 256) {
        int l = i >> 5, n4 = (i & 31) * 4;
        int tok = c * QC + l;
        float4 cv = {0, 0, 0, 0};
        if (tok < SEQL)
            cv = *(const float4*)(xbc + (size_t)(b * SEQL + tok) * CONVDIM + DINNER + DSTATE + n4);
        sC[l * SCW + n4 + 0] = f2bf(cv.x); sC[l * SCW + n4 + 1] = f2bf(cv.y);
        sC[l * SCW + n4 + 2] = f2bf(cv.z); sC[l * SCW + n4 + 3] = f2bf(cv.w);
        float4 sv = *(const float4*)(Sg + (size_t)bid * 8192 + l * 128 + n4);
        sS[l * SCW + n4 + 0] = f2bf(sv.x); sS[l * SCW + n4 + 1] = f2bf(sv.y);
        sS[l * SCW + n4 + 2] = f2bf(sv.z); sS[l * SCW + n4 + 3] = f2bf(sv.w);
    }
    __syncthreads();
    int fr = lane & 15, fk8 = (lane >> 4) * 8;
    int wr = wave >> 1, wc = wave & 1;
    fx4 yo[2][2] = {};
    #pragma unroll
    for (int k = 0; k < 4; ++k) {
        bfx8 a0 = *(const bfx8*)&sC[(wr * 32 + fr) * SCW + k * 32 + fk8];
        bfx8 a1 = *(const bfx8*)&sC[(wr * 32 + 16 + fr) * SCW + k * 32 + fk8];
        bfx8 b0 = *(const bfx8*)&sS[(wc * 32 + fr) * SCW + k * 32 + fk8];
        bfx8 b1 = *(const bfx8*)&sS[(wc * 32 + 16 + fr) * SCW + k * 32 + fk8];
        yo[0][0] = __builtin_amdgcn_mfma_f32_16x16x32_bf16(a0, b0, yo[0][0], 0, 0, 0);
        yo[0][1] = __builtin_amdgcn_mfma_f32_16x16x32_bf16(a0, b1, yo[0][1], 0, 0, 0);
        yo[1][0] = __builtin_amdgcn_mfma_f32_16x16x32_bf16(a1, b0, yo[1][0], 0, 0, 0);
        yo[1][1] = __builtin_amdgcn_mfma_f32_16x16x32_bf16(a1, b1, yo[1][1], 0, 0, 0);
    }
    int rb = wr * 32 + (lane >> 4) * 4;
    int cb = wc * 32 + fr;
    #pragma unroll
    for (int m = 0; m < 2; ++m)
        #pragma unroll
        for (int i = 0; i < 4; ++i) {
            int row = rb + m * 16 + i;
            int tok = c * QC + row;
            if (tok < SEQL) {
                float e = sE[row];
                #pragma unroll
                for (int n = 0; n < 2; ++n) {
                    int col = cb + n * 16;
                    size_t off = (size_t)(b * SEQL + tok) * DINNER + h * 64 + col;
                    ybuf[off] += yo[m][n][i] * e;
                }
            }
        }
}

// ---------------- gate (y * silu(z)) + RMSNorm + norm_w, output bf16 (padded) ----
__global__ __launch_bounds__(256) void k_norm(const float* __restrict__ ybuf,
                                              const float* __restrict__ zx,
                                              const float* __restrict__ normw,
                                              unsigned short* __restrict__ ynb) {
    int row = blockIdx.x;
    int t = threadIdx.x;
    if (row >= TOKENS) {
        #pragma unroll
        for (int j = 0; j < 8; ++j) ynb[(size_t)row * DINNER + t + j * 256] = 0;
        return;
    }
    float v[8];
    float ss = 0.f;
    #pragma unroll
    for (int j = 0; j < 8; ++j) {
        int col = t + j * 256;
        float y = ybuf[(size_t)row * DINNER + col];
        float z = zx[(size_t)row * NPROJ + col];
        y *= z / (1.f + expf(-z));
        v[j] = y;
        ss += y * y;
    }
    #pragma unroll
    for (int off = 32; off > 0; off >>= 1) ss += __shfl_down(ss, off, 64);
    __shared__ float red[4];
    int lane = t & 63, wv = t >> 6;
    if (lane == 0) red[wv] = ss;
    __syncthreads();
    float tot = red[0] + red[1] + red[2] + red[3];
    float r = rsqrtf(tot * (1.f / DINNER) + 1e-5f);
    #pragma unroll
    for (int j = 0; j < 8; ++j) {
        int col = t + j * 256;
        ynb[(size_t)row * DINNER + col] = f2bf(v[j] * r * normw[col]);
    }
}

extern "C" void kernel_launch(void* const* d_in, const int* in_sizes, int n_in,
                              void* d_out, int out_size, void* d_ws, size_t ws_size,
                              hipStream_t stream) {
    const float* x       = (const float*)d_in[0];
    const float* W_in    = (const float*)d_in[1];
    const float* conv_w  = (const float*)d_in[2];
    const float* conv_b  = (const float*)d_in[3];
    const float* dt_bias = (const float*)d_in[4];
    const float* A_log   = (const float*)d_in[5];
    const float* Dp      = (const float*)d_in[6];
    const float* norm_w  = (const float*)d_in[7];
    const float* W_out   = (const float*)d_in[8];
    float* out = (float*)d_out;

    char* w = (char*)d_ws;
    auto alloc = [&](size_t bytes) {
        char* p = w;
        w += (bytes + 255) & ~(size_t)255;
        return p;
    };
    unsigned short* xb    = (unsigned short*)alloc((size_t)MPAD * DMODEL * 2);
    unsigned short* winb  = (unsigned short*)alloc((size_t)NPAD1 * DMODEL * 2);
    unsigned short* woutb = (unsigned short*)alloc((size_t)DMODEL * DINNER * 2);
    float* zx   = (float*)alloc((size_t)TOKENS * NPROJ * 4);   // reused as split-K partials for gemm2
    float* xbc  = (float*)alloc((size_t)TOKENS * CONVDIM * 4);
    float* dtv  = (float*)alloc((size_t)TOKENS * NHEADS * 4);
    float* yb   = (float*)alloc((size_t)TOKENS * DINNER * 4);
    unsigned short* ynb = (unsigned short*)alloc((size_t)MPAD * DINNER * 2);
    float* Sg   = (float*)alloc((size_t)BATCHN * NHEADS * NCH * HEADDIM * DSTATE * 4);
    float* cumA = (float*)alloc((size_t)BATCHN * NHEADS * NCH * 64 * 4);

    int n4;
    n4 = MPAD * DMODEL / 4;
    k_f2bf_pad<<<(n4 + 255) / 256, 256, 0, stream>>>(x, xb, TOKENS * DMODEL / 4, n4);
    n4 = NPAD1 * DMODEL / 4;
    k_f2bf_pad<<<(n4 + 255) / 256, 256, 0, stream>>>(W_in, winb, NPROJ * DMODEL / 4, n4);
    n4 = DMODEL * DINNER / 4;
    k_f2bf_pad<<<(n4 + 255) / 256, 256, 0, stream>>>(W_out, woutb, n4, n4);
    k_dt<<<TOKENS / 8, 256, 0, stream>>>(x, W_in, dt_bias, dtv);
    // GEMM1: zx[2000][4384] = xb[2048][1024] * winb[4608][1024]^T
    dim3 g1(NPAD1 / 256, MPAD / 128, 1);
    k_gemm256<<<g1, 512, 0, stream>>>(xb, winb, zx, TOKENS, NPROJ, DMODEL, DMODEL, 0);
    k_conv<<<(TOKENS * CONVDIM + 255) / 256, 256, 0, stream>>>(zx, conv_w, conv_b, xbc);
    k_tile<<<BATCHN * NHEADS * NCH, 256, 0, stream>>>(xbc, dtv, A_log, Dp, yb, Sg, cumA);
    k_scan2v<<<BATCHN * NHEADS * 32, 256, 0, stream>>>(Sg, cumA);
    k_yoff<<<BATCHN * NHEADS * NCH, 256, 0, stream>>>(xbc, Sg, cumA, yb);
    k_norm<<<MPAD, 256, 0, stream>>>(yb, zx, norm_w, ynb);
    // GEMM2 split-K=4: partials into zx (dead after k_norm), then reduce
    size_t pstride = (size_t)MPAD * DMODEL;
    dim3 g2(DMODEL / 256, MPAD / 128, 4);
    k_gemm256<<<g2, 512, 0, stream>>>(ynb, woutb, zx, MPAD, DMODEL, DINNER, DINNER / 4, pstride);
    n4 = TOKENS * DMODEL / 4;
    k_red<<<(n4 + 255) / 256, 256, 0, stream>>>(zx, out, n4, pstride / 4);
}